// Round 9
// baseline (762.901 us; speedup 1.0000x reference)
//
#include <hip/hip_runtime.h>
#include <hip/hip_bf16.h>

#define TB 256
#define TBM 512   // MFMA kernels: 8 waves/block
#define BM 64
#define BK 32
#define BN 128
#define ASTR 68   // BM + 4 (fp32 path)
#define MAXD 160  // per-node edge cache for k5

static constexpr int NN = 20000;
static constexpr int NE = 320000;
static constexpr int NB = 313;    // ceil(NN/64)

// workspace layout (floats) — FIXED: owH/owL are E*128 ushorts EACH (40.96M floats total)
static constexpr long long OFF_OW  = 0;           // owH [0..20.48M), owL [20.48M..40.96M)
static constexpr long long OFF_PQ  = 40960000;    // time-shared N*256 slot: P -> hagg -> Q
static constexpr long long OFF_S   = 46080000;    // E
static constexpr long long OFF_DEN = 46400000;    // N
static constexpr long long OFF_CUR = 46420000;    // N ints
static constexpr long long OFF_WT  = 46440000;    // split weights: 131072 ushorts = 65536 floats
static constexpr long long OFF_C2  = 46505536;    // 128*128 f32
static constexpr long long WS_FLOATS = 46525000;  // ~186.1 MB (< proven 196.6 MB budget)

// wt ushort offsets
static constexpr int U_E2H = 0;       // [256 col][128 k]  ([We|We@Wf3]^T split)
static constexpr int U_E2L = 32768;
static constexpr int U_A2H = 65536;   // [128 col][256 k'] (Wa rows 256..511 ^T split)
static constexpr int U_A2L = 98304;

// d_out layout (floats)
static constexpr long long OUT_HOUT = 0;
static constexpr long long OUT_WOUT = 2560000;    // holds hnP until k7p writes w_out
static constexpr long long OUT_SAT  = 43520000;

typedef __attribute__((ext_vector_type(8))) short s8v;
typedef __attribute__((ext_vector_type(4))) float f32x4;

#define MFMA16(a,b,c) __builtin_amdgcn_mfma_f32_16x16x32_bf16(a,b,c,0,0,0)

__device__ __forceinline__ float lrelu(float x){ return x >= 0.f ? x : 0.1f*x; }

__device__ __forceinline__ void gl16(const void* g, void* l){
    __builtin_amdgcn_global_load_lds(
        (const __attribute__((address_space(1))) void*)g,
        (__attribute__((address_space(3))) void*)l, 16, 0, 0);
}

__device__ __forceinline__ void split1(float f, unsigned short& hi, unsigned short& lo){
    __hip_bfloat16 h = __float2bfloat16(f);
    float hf = __bfloat162float(h);
    __hip_bfloat16 l = __float2bfloat16(f - hf);
    hi = __builtin_bit_cast(unsigned short, h);
    lo = __builtin_bit_cast(unsigned short, l);
}
__device__ __forceinline__ void split8(float4 a, float4 b, s8v& hi, s8v& lo){
    float v[8] = {a.x,a.y,a.z,a.w,b.x,b.y,b.z,b.w};
#pragma unroll
    for (int j = 0; j < 8; ++j){
        unsigned short hs, ls;
        split1(v[j], hs, ls);
        hi[j] = (short)hs; lo[j] = (short)ls;
    }
}
// packed u32 (hi<<16|lo) -> fp32
__device__ __forceinline__ float bfp(unsigned p){
    return __uint_as_float(p & 0xffff0000u) + __uint_as_float(p << 16);
}

// ================= fp32 GEMM helpers =================
__device__ __forceinline__ void store_At(float (*Ast)[ASTR], int k4, int r, float4 v){
    Ast[k4+0][r] = v.x; Ast[k4+1][r] = v.y; Ast[k4+2][r] = v.z; Ast[k4+3][r] = v.w;
}
__device__ __forceinline__ void mm_chunk(const float (*Ast)[ASTR], const float (*Bs)[BN],
                                         int r0, int c0, float acc[4][8]){
#pragma unroll 4
    for (int k = 0; k < BK; ++k){
        const float4 av = *(const float4*)&Ast[k][r0];
        const float4 b0 = *(const float4*)&Bs[k][c0];
        const float4 b1 = *(const float4*)&Bs[k][64 + c0];
        const float a0=av.x, a1=av.y, a2=av.z, a3=av.w;
        const float b[8] = {b0.x,b0.y,b0.z,b0.w,b1.x,b1.y,b1.z,b1.w};
#pragma unroll
        for (int j = 0; j < 8; ++j){
            acc[0][j] = fmaf(a0, b[j], acc[0][j]);
            acc[1][j] = fmaf(a1, b[j], acc[1][j]);
            acc[2][j] = fmaf(a2, b[j], acc[2][j]);
            acc[3][j] = fmaf(a3, b[j], acc[3][j]);
        }
    }
}
__device__ __forceinline__ void load_B(const float* __restrict__ W, int kc,
                                       float (*Bs)[BN], int tid){
#pragma unroll
    for (int p = 0; p < 4; ++p){
        int idx = p*TB + tid;
        int row = idx >> 5;
        int c4  = (idx & 31) << 2;
        *(float4*)&Bs[row][c4] = *(const float4*)&W[(size_t)(kc+row)*BN + c4];
    }
}

// ---------------- kC2: C2 = We @ Wf3 (fp32, 128x128) ----------------
__global__ __launch_bounds__(TB) void kC2(const float* __restrict__ We,
                                          const float* __restrict__ Wf3,
                                          float* __restrict__ C2){
    __shared__ float Ast[BK][ASTR];
    __shared__ float Bs[BK][BN];
    const int tid = threadIdx.x;
    const int rbase = blockIdx.x * BM;
    const int tc = tid & 15, tr = tid >> 4;
    const int r0 = tr*4, c0 = tc*4;
    float acc[4][8] = {};
    for (int kc = 0; kc < 128; kc += BK){
        __syncthreads();
        {
            int lr = tid >> 3, k4 = (tid & 7) << 2;
#pragma unroll
            for (int p = 0; p < 2; ++p){
                int r = p*32 + lr;
                float4 v = *(const float4*)&We[(size_t)(rbase+r)*128 + kc + k4];
                store_At(Ast, k4, r, v);
            }
        }
        load_B(Wf3, kc, Bs, tid);
        __syncthreads();
        mm_chunk(Ast, Bs, r0, c0, acc);
    }
#pragma unroll
    for (int i = 0; i < 4; ++i){
        int rr = rbase + r0 + i;
        float4 o0 = {acc[i][0],acc[i][1],acc[i][2],acc[i][3]};
        float4 o1 = {acc[i][4],acc[i][5],acc[i][6],acc[i][7]};
        *(float4*)&C2[(size_t)rr*128 + c0] = o0;
        *(float4*)&C2[(size_t)rr*128 + 64 + c0] = o1;
    }
}

// ---------------- kP2: cur init + split/transpose [We|C2] and Wa[256:512] ----------------
__global__ __launch_bounds__(TB) void kP2(const float* __restrict__ We,
                                          const float* __restrict__ C2,
                                          const float* __restrict__ Wa,
                                          unsigned short* __restrict__ wt,
                                          int* __restrict__ cur){
    int id = blockIdx.x*TB + threadIdx.x;   // grid covers 65536
    if (id < NN) cur[id] = 0;
    unsigned short hs, ls;
    if (id < 32768){                        // wtE2: col<256, k<128
        int col = id >> 7, k = id & 127;
        float v = (col < 128) ? We[(size_t)k*128 + col] : C2[(size_t)k*128 + (col-128)];
        split1(v, hs, ls);
        wt[U_E2H + id] = hs; wt[U_E2L + id] = ls;
    } else if (id < 65536){                 // wtA2: col<128, k'<256 (global k = 256+k')
        int local = id - 32768;
        int col = local >> 8, kk = local & 255;
        split1(Wa[(size_t)(256+kk)*128 + col], hs, ls);
        wt[U_A2H + local] = hs; wt[U_A2L + local] = ls;
    }
}

// ---------------- sort pipeline ----------------
__global__ __launch_bounds__(TB) void kB_count(const int* __restrict__ dst,
                                               int* __restrict__ cur){
    int e = blockIdx.x*TB + threadIdx.x;
    atomicAdd(&cur[dst[e]], 1);
}
__global__ __launch_bounds__(TB) void kC_scan(int* __restrict__ cur,
                                              int* __restrict__ offs){
    __shared__ int part[TB];
    __shared__ int spre[TB];
    const int tid = threadIdx.x;
    const int CH = (NN + TB - 1) / TB;
    const int base = tid * CH;
    int sum = 0;
    for (int i = 0; i < CH; ++i){ int idx = base + i; if (idx < NN) sum += cur[idx]; }
    part[tid] = sum;
    __syncthreads();
    if (tid == 0){ int r = 0; for (int i = 0; i < TB; ++i){ spre[i] = r; r += part[i]; } }
    __syncthreads();
    int run = spre[tid];
    for (int i = 0; i < CH; ++i){
        int idx = base + i;
        if (idx < NN){ int c = cur[idx]; offs[idx] = run; cur[idx] = run; run += c; }
    }
}
__global__ __launch_bounds__(TB) void kD_scatter(const int* __restrict__ dst,
                                                 int* __restrict__ cur,
                                                 int* __restrict__ eidx){
    int e = blockIdx.x*TB + threadIdx.x;
    int p = atomicAdd(&cur[dst[e]], 1);
    eidx[p] = e;
}

// ---------------- k1: hn = h @ W_node -> hnP packed ----------------
__global__ __launch_bounds__(TB) void k1_hn(const float* __restrict__ h,
                                            const float* __restrict__ Wn,
                                            unsigned* __restrict__ hnP){
    __shared__ float Ast[BK][ASTR];
    __shared__ float Bs[BK][BN];
    const int tid = threadIdx.x;
    const int rbase = blockIdx.x * BM;
    const int tc = tid & 15, tr = tid >> 4;
    const int r0 = tr*4, c0 = tc*4;
    float acc[4][8] = {};
    for (int kc = 0; kc < 128; kc += BK){
        __syncthreads();
        {
            int lr = tid >> 3, k4 = (tid & 7) << 2;
#pragma unroll
            for (int p = 0; p < 2; ++p){
                int r = p*32 + lr;
                int rr = rbase + r; if (rr >= NN) rr = NN-1;
                float4 v = *(const float4*)&h[(size_t)rr*128 + kc + k4];
                store_At(Ast, k4, r, v);
            }
        }
        load_B(Wn, kc, Bs, tid);
        __syncthreads();
        mm_chunk(Ast, Bs, r0, c0, acc);
    }
#pragma unroll
    for (int i = 0; i < 4; ++i){
        int rr = rbase + r0 + i;
        if (rr < NN){
            uint4 p0, p1;
#pragma unroll
            for (int j = 0; j < 4; ++j){
                unsigned short hs, ls;
                split1(acc[i][j], hs, ls);
                ((unsigned*)&p0)[j] = ((unsigned)hs << 16) | ls;
                split1(acc[i][4+j], hs, ls);
                ((unsigned*)&p1)[j] = ((unsigned)hs << 16) | ls;
            }
            *(uint4*)&hnP[(size_t)rr*128 + c0] = p0;
            *(uint4*)&hnP[(size_t)rr*128 + 64 + c0] = p1;
        }
    }
}

// ---------------- kNG: O[n][half*128..+128] = A @ W_half (fp32; A packed or fp32) ----------------
__global__ __launch_bounds__(TB) void kNG(const unsigned* __restrict__ aP,
                                          const float* __restrict__ aF,
                                          int packed,
                                          const float* __restrict__ W,   // [>=256][128] rows
                                          float* __restrict__ O){        // [N][256]
    __shared__ float Ast[BK][ASTR];
    __shared__ float Bs[BK][BN];
    const int tid = threadIdx.x;
    const int half = blockIdx.x >= NB ? 1 : 0;
    const int rbase = (blockIdx.x - half*NB) * BM;
    const float* Wp = W + (size_t)half*16384;
    const int tc = tid & 15, tr = tid >> 4;
    const int r0 = tr*4, c0 = tc*4;
    float acc[4][8] = {};
    for (int kc = 0; kc < 128; kc += BK){
        __syncthreads();
        {
            int lr = tid >> 3, k4 = (tid & 7) << 2;
#pragma unroll
            for (int p = 0; p < 2; ++p){
                int r = p*32 + lr;
                int rr = rbase + r; if (rr >= NN) rr = NN-1;
                float4 v;
                if (packed){
                    uint4 q = *(const uint4*)&aP[(size_t)rr*128 + kc + k4];
                    v.x = bfp(q.x); v.y = bfp(q.y); v.z = bfp(q.z); v.w = bfp(q.w);
                } else {
                    v = *(const float4*)&aF[(size_t)rr*128 + kc + k4];
                }
                store_At(Ast, k4, r, v);
            }
        }
        load_B(Wp, kc, Bs, tid);
        __syncthreads();
        mm_chunk(Ast, Bs, r0, c0, acc);
    }
#pragma unroll
    for (int i = 0; i < 4; ++i){
        int rr = rbase + r0 + i;
        if (rr < NN){
            float4 o0 = {acc[i][0],acc[i][1],acc[i][2],acc[i][3]};
            float4 o1 = {acc[i][4],acc[i][5],acc[i][6],acc[i][7]};
            *(float4*)&O[(size_t)rr*256 + half*128 + c0] = o0;
            *(float4*)&O[(size_t)rr*256 + half*128 + 64 + c0] = o1;
        }
    }
}

// ================== k2_mega: ew @ [We | We@Wf3] (64 edges x 256 cols, K=128) ==================
// epilogues: p (esf-dot), w1 -> sat + ow splits, s = attn-dot(lrelu(p*u + P1[src]+P2[dst]+bf)),
//            sat hs/hd gather-copy
__global__ __launch_bounds__(TBM) void k2_mega(const float* __restrict__ ew,
                                               const unsigned short* __restrict__ wtH,
                                               const unsigned short* __restrict__ wtL,
                                               const float* __restrict__ Wesf,
                                               const float* __restrict__ Wattn,
                                               const float* __restrict__ bf,
                                               const float* __restrict__ P,
                                               const unsigned* __restrict__ hnP,
                                               const int* __restrict__ src,
                                               const int* __restrict__ dst,
                                               unsigned short* __restrict__ owH,
                                               unsigned short* __restrict__ owL,
                                               float* __restrict__ sat,
                                               float* __restrict__ s_ws){
    __shared__ __align__(16) unsigned short Ah[2][2048], Al[2][2048];
    __shared__ __align__(16) unsigned short Bh[2][8192], Bl[2][8192];
    // epilogue scratch aliases Ah[0] (dead after GEMM): 768 floats = 3072 B < 4096 B
    float* eEsf = (float*)&Ah[0][0];
    float* eAtt = eEsf + 128;
    float* eBf  = eAtt + 128;
    float* ePl  = eBf + 128;     // [64][2]
    float* eSl  = ePl + 128;     // [64][2]
    int*   eSrc = (int*)(eSl + 128);
    int*   eDst = eSrc + 64;
    const int tid = threadIdx.x;
    const long long rbase = (long long)blockIdx.x * 64;
    const int lane = tid & 63, w = tid >> 6;
    const int ls = lane & 15, lg = lane >> 4;
    const int rgrp = w & 1, cg = w >> 1;
    f32x4 acc[2][4] = {};
    auto stage = [&](int nb, int t){
        const int kc = t*32;
#pragma unroll
        for (int q = 0; q < 2; ++q){
            int col = q*128 + w*16 + (lane>>2);
            int g = (lane&3) ^ (col&3);
            gl16(&wtH[col*128 + kc + g*8], &Bh[nb][q*4096 + w*512]);
            gl16(&wtL[col*128 + kc + g*8], &Bl[nb][q*4096 + w*512]);
        }
        if (tid < 256){
            int srow = tid >> 2, sg = tid & 3;
            const float* p = &ew[(rbase + srow)*128 + kc + sg*8];
            float4 v0 = *(const float4*)p, v1 = *(const float4*)(p+4);
            s8v hi, lo; split8(v0, v1, hi, lo);
            int slot = srow*32 + ((sg ^ (srow&3)) << 3);
            *(s8v*)&Ah[nb][slot] = hi; *(s8v*)&Al[nb][slot] = lo;
        }
    };
    stage(0, 0);
    __syncthreads();
    int cur = 0;
    for (int t = 0; t < 4; ++t){
        if (t+1 < 4) stage(cur^1, t+1);
        s8v ah[2], al[2];
#pragma unroll
        for (int rt = 0; rt < 2; ++rt){
            int r = rgrp*32 + rt*16 + ls;
            int idx = r*32 + ((lg ^ (r&3)) << 3);
            ah[rt] = *(const s8v*)&Ah[cur][idx];
            al[rt] = *(const s8v*)&Al[cur][idx];
        }
#pragma unroll
        for (int ct = 0; ct < 4; ++ct){
            int c = cg*64 + ct*16 + ls;
            int idx = c*32 + ((lg ^ (c&3)) << 3);
            s8v bh = *(const s8v*)&Bh[cur][idx];
            s8v bl = *(const s8v*)&Bl[cur][idx];
#pragma unroll
            for (int rt = 0; rt < 2; ++rt){
                acc[rt][ct] = MFMA16(ah[rt], bh, acc[rt][ct]);
                acc[rt][ct] = MFMA16(ah[rt], bl, acc[rt][ct]);
                acc[rt][ct] = MFMA16(al[rt], bh, acc[rt][ct]);
            }
        }
        __syncthreads();
        cur ^= 1;
    }
    // E0: load consts into aliased scratch
    if (tid < 128){ eEsf[tid] = Wesf[tid]; eAtt[tid] = Wattn[tid]; eBf[tid] = bf[tid]; }
    if (tid < 64){ eSrc[tid] = src[rbase + tid]; eDst[tid] = dst[rbase + tid]; }
    __syncthreads();
    // E1: waves 0-3 p-partials; waves 4-7 sat hs/hd gather-copy
    if (cg < 2){
#pragma unroll
        for (int rt = 0; rt < 2; ++rt){
#pragma unroll
            for (int reg = 0; reg < 4; ++reg){
                float pp = 0.f;
#pragma unroll
                for (int ct = 0; ct < 4; ++ct){
                    int col = cg*64 + ct*16 + ls;
                    pp += lrelu(acc[rt][ct][reg]) * eEsf[col];
                }
#pragma unroll
                for (int m = 1; m < 16; m <<= 1) pp += __shfl_xor(pp, m);
                int row = rgrp*32 + rt*16 + lg*4 + reg;
                if (ls == 0) ePl[row*2 + cg] = pp;
            }
        }
    } else {
        int wv = w - 4;
        for (int i = lane; i < 1024; i += 64){
            int row = wv*16 + (i >> 6), q = i & 63;
            int node = (q < 32) ? eSrc[row] : eDst[row];
            uint4 pv = *(const uint4*)&hnP[(size_t)node*128 + ((q & 31) << 2)];
            float4 v = {bfp(pv.x), bfp(pv.y), bfp(pv.z), bfp(pv.w)};
            *(float4*)&sat[(rbase + row)*384 + q*4] = v;
        }
    }
    __syncthreads();
    // E2: waves 0-3 w1/ow writes; waves 4-7 s-partials
    if (cg < 2){
#pragma unroll
        for (int rt = 0; rt < 2; ++rt){
#pragma unroll
            for (int reg = 0; reg < 4; ++reg){
                int row = rgrp*32 + rt*16 + lg*4 + reg;
                float pr = ePl[row*2] + ePl[row*2 + 1];
                long long orow = rbase + row;
#pragma unroll
                for (int ct = 0; ct < 4; ++ct){
                    int col = cg*64 + ct*16 + ls;
                    float o = acc[rt][ct][reg];
                    sat[orow*384 + 256 + col] = pr * o;
                    unsigned short hs_, ls_; split1(o, hs_, ls_);
                    owH[orow*128 + col] = hs_;
                    owL[orow*128 + col] = ls_;
                }
            }
        }
    } else {
#pragma unroll
        for (int rt = 0; rt < 2; ++rt){
#pragma unroll
            for (int reg = 0; reg < 4; ++reg){
                int row = rgrp*32 + rt*16 + lg*4 + reg;
                float pr = ePl[row*2] + ePl[row*2 + 1];
                int sI = eSrc[row], dI = eDst[row];
                float sp = 0.f;
#pragma unroll
                for (int ct = 0; ct < 4; ++ct){
                    int c = (cg-2)*64 + ct*16 + ls;
                    float val = pr * acc[rt][ct][reg]
                              + P[(size_t)sI*256 + c]
                              + P[(size_t)dI*256 + 128 + c]
                              + eBf[c];
                    sp += lrelu(val) * eAtt[c];
                }
#pragma unroll
                for (int m = 1; m < 16; m <<= 1) sp += __shfl_xor(sp, m);
                if (ls == 0) eSl[row*2 + (cg-2)] = sp;
            }
        }
    }
    __syncthreads();
    if (tid < 64) s_ws[rbase + tid] = eSl[tid*2] + eSl[tid*2 + 1];
}

// ---------------- k5: wave-per-node softmax + gather-aggregate ----------------
__global__ __launch_bounds__(TB) void k5_agg(const float* __restrict__ s,
                                             const unsigned* __restrict__ hnP,
                                             const float* __restrict__ sat,
                                             const int* __restrict__ src,
                                             const int* __restrict__ eidx,
                                             const int* __restrict__ offs,
                                             const int* __restrict__ cur,
                                             float* __restrict__ hagg,
                                             float* __restrict__ den){
    __shared__ int   sEu[4][MAXD];
    __shared__ int   sEs[4][MAXD];
    __shared__ float sAl[4][MAXD];
    __shared__ float sWc[4][MAXD];
    const int wv = threadIdx.x >> 6, lane = threadIdx.x & 63;
    const int n = blockIdx.x*4 + wv;
    int* Eu = sEu[wv]; int* Es = sEs[wv];
    float* Al = sAl[wv]; float* Wc = sWc[wv];
    const int start = offs[n];
    const int deg = cur[n] - start;
    const int dc = deg < MAXD ? deg : MAXD;
    for (int i = lane; i < dc; i += 64) Eu[i] = eidx[start+i];
    __syncthreads();
    for (int i = lane; i < dc; i += 64){
        int my = Eu[i], r = 0;
        for (int j = 0; j < dc; ++j) r += (Eu[j] < my);
        Es[r] = my;
    }
    __syncthreads();
    float lm = -3.402823466e38f;
    for (int i = lane; i < dc; i += 64){
        int e = Es[i];
        float sv = s[e];
        Wc[i] = sv;
        Eu[i] = src[e];
        lm = fmaxf(lm, sv);
    }
    for (int i = MAXD + lane; i < deg; i += 64) lm = fmaxf(lm, s[eidx[start+i]]);
#pragma unroll
    for (int m2 = 32; m2; m2 >>= 1) lm = fmaxf(lm, __shfl_xor(lm, m2));
    const float m = lm;
    float lsum = 0.f;
    for (int i = lane; i < dc; i += 64){
        float ev = expf(Wc[i] - m);
        Al[i] = ev;
        lsum += ev;
    }
    for (int i = MAXD + lane; i < deg; i += 64) lsum += expf(s[eidx[start+i]] - m);
#pragma unroll
    for (int m2 = 32; m2; m2 >>= 1) lsum += __shfl_xor(lsum, m2);
    const float denom = lsum;
    const float inv = (deg > 0) ? 1.f/denom : 0.f;
    for (int i = lane; i < dc; i += 64){
        float al = Al[i] * inv;
        Al[i] = al;
        Wc[i] = al * Wc[i];
    }
    __syncthreads();
    float a0=0.f, a1=0.f, a2=0.f, a3=0.f;
    for (int i = 0; i < dc; ++i){
        int sI = Eu[i];
        size_t e = (size_t)Es[i];
        float al = Al[i], wc = Wc[i];
        unsigned p0 = hnP[(size_t)sI*128 + lane];
        unsigned p1 = hnP[(size_t)sI*128 + 64 + lane];
        float w0 = sat[e*384 + 256 + lane];
        float w1v = sat[e*384 + 256 + 64 + lane];
        a0 = fmaf(al, bfp(p0), a0);
        a1 = fmaf(al, bfp(p1), a1);
        a2 = fmaf(wc, w0, a2);
        a3 = fmaf(wc, w1v, a3);
    }
    for (int i = MAXD; i < deg; ++i){
        int e = eidx[start+i];
        float sv = s[e];
        float al = expf(sv - m) * inv;
        float wc = al * sv;
        int sI = src[e];
        a0 = fmaf(al, bfp(hnP[(size_t)sI*128 + lane]), a0);
        a1 = fmaf(al, bfp(hnP[(size_t)sI*128 + 64 + lane]), a1);
        a2 = fmaf(wc, sat[(size_t)e*384 + 256 + lane], a2);
        a3 = fmaf(wc, sat[(size_t)e*384 + 256 + 64 + lane], a3);
    }
    const size_t b = (size_t)n*256;
    hagg[b + lane] = a0;
    hagg[b + 64 + lane] = a1;
    hagg[b + 128 + lane] = a2;
    hagg[b + 192 + lane] = a3;
    if (lane == 0) den[n] = (deg > 0) ? denom : 0.f;
}

// ---------------- k6: h_new = [h_agg, hn] @ W_conc + b_conc ; indeg select ----------------
__global__ __launch_bounds__(TB) void k6_conc(const float* __restrict__ hagg,
                                              const unsigned* __restrict__ hnP,
                                              const float* __restrict__ Wc,
                                              const float* __restrict__ bc,
                                              const float* __restrict__ den,
                                              float* __restrict__ hout){
    __shared__ float Ast[BK][ASTR];
    __shared__ float Bs[BK][BN];
    __shared__ float sBc[BN];
    const int tid = threadIdx.x;
    const int rbase = blockIdx.x * BM;
    const int tc = tid & 15, tr = tid >> 4;
    const int r0 = tr*4, c0 = tc*4;
    if (tid < BN) sBc[tid] = bc[tid];
    float acc[4][8] = {};
    for (int chunk = 0; chunk < 12; ++chunk){
        int kc = chunk * BK;
        __syncthreads();
        {
            int lr = tid >> 3, k4 = (tid & 7) << 2;
#pragma unroll
            for (int p = 0; p < 2; ++p){
                int r = p*32 + lr;
                int rr = rbase + r; if (rr >= NN) rr = NN-1;
                float4 v;
                if (chunk < 8) v = *(const float4*)&hagg[(size_t)rr*256 + kc + k4];
                else {
                    int cb = (kc - 256) + k4;
                    uint4 q = *(const uint4*)&hnP[(size_t)rr*128 + cb];
                    v.x = bfp(q.x); v.y = bfp(q.y); v.z = bfp(q.z); v.w = bfp(q.w);
                }
                store_At(Ast, k4, r, v);
            }
        }
        load_B(Wc, kc, Bs, tid);
        __syncthreads();
        mm_chunk(Ast, Bs, r0, c0, acc);
    }
#pragma unroll
    for (int i = 0; i < 4; ++i){
        int rr = rbase + r0 + i;
        if (rr >= NN) continue;
        bool keep = den[rr] > 0.f;
        float o[8];
#pragma unroll
        for (int j = 0; j < 8; ++j){
            int col = (j < 4) ? (c0 + j) : (60 + c0 + j);
            float fb = bfp(hnP[(size_t)rr*128 + col]);
            o[j] = keep ? acc[i][j] + sBc[col] : fb;
        }
        float4 o0 = {o[0],o[1],o[2],o[3]}, o1 = {o[4],o[5],o[6],o[7]};
        *(float4*)&hout[(size_t)rr*128 + c0] = o0;
        *(float4*)&hout[(size_t)rr*128 + 64 + c0] = o1;
    }
}

// ---------------- k7p: w_out = [w_bn, ow] @ Wa[256:512] + Q1[src] + Q2[dst] ----------------
__global__ __launch_bounds__(TBM) void k7p(const unsigned short* __restrict__ owH,
                                           const unsigned short* __restrict__ owL,
                                           const float* __restrict__ sarr,
                                           const float* __restrict__ sat,
                                           const float* __restrict__ Q,
                                           const float* __restrict__ gamma,
                                           const float* __restrict__ beta,
                                           const unsigned short* __restrict__ wtH,  // [128][256]
                                           const unsigned short* __restrict__ wtL,
                                           const int* __restrict__ src,
                                           const int* __restrict__ dst,
                                           float* __restrict__ w2out){
    __shared__ __align__(16) unsigned short Ah[2][4096], Al[2][4096], Bh[2][4096], Bl[2][4096];
    __shared__ float sGam[128], sBet[128], sS[128];
    __shared__ int sSrc[128], sDst[128];
    const int tid = threadIdx.x;
    const long long rbase = (long long)blockIdx.x * 128;
    const int lane = tid & 63, w = tid >> 6;
    const int ls = lane & 15, lg = lane >> 4;
    const int srow = tid >> 2, sg = tid & 3;
    const int gsw = sg ^ (srow & 3);
    const int aslot = srow*32 + (gsw << 3);
    const float ISR = 0.9999950000374997f;  // 1/sqrt(1+1e-5)
    if (tid < 128){
        sGam[tid] = gamma[tid] * ISR; sBet[tid] = beta[tid];
        sSrc[tid] = src[rbase + tid]; sDst[tid] = dst[rbase + tid];
        sS[tid] = sarr[rbase + tid];
    }
    __syncthreads();
    f32x4 acc[8] = {};
    auto stage = [&](int nb, int t){
        const int kc = t*32;
        gl16(&wtH[srow*256 + kc + gsw*8], &Bh[nb][w*512]);
        gl16(&wtL[srow*256 + kc + gsw*8], &Bl[nb][w*512]);
        long long e = rbase + srow;
        if (kc < 128){
            int cb = kc + sg*8;
            float se = sS[srow];
            const float* p = &sat[e*384 + 256 + cb];   // w1
            float4 v0 = *(const float4*)p, v1 = *(const float4*)(p+4);
            v0.x = fmaf(v0.x*se, sGam[cb+0], sBet[cb+0]);
            v0.y = fmaf(v0.y*se, sGam[cb+1], sBet[cb+1]);
            v0.z = fmaf(v0.z*se, sGam[cb+2], sBet[cb+2]);
            v0.w = fmaf(v0.w*se, sGam[cb+3], sBet[cb+3]);
            v1.x = fmaf(v1.x*se, sGam[cb+4], sBet[cb+4]);
            v1.y = fmaf(v1.y*se, sGam[cb+5], sBet[cb+5]);
            v1.z = fmaf(v1.z*se, sGam[cb+6], sBet[cb+6]);
            v1.w = fmaf(v1.w*se, sGam[cb+7], sBet[cb+7]);
            s8v hi, lo; split8(v0, v1, hi, lo);
            *(s8v*)&Ah[nb][aslot] = hi; *(s8v*)&Al[nb][aslot] = lo;
        } else {
            int col0 = kc - 128;
            gl16(&owH[e*128 + col0 + gsw*8], &Ah[nb][w*512]);
            gl16(&owL[e*128 + col0 + gsw*8], &Al[nb][w*512]);
        }
    };
    stage(0, 0);
    __syncthreads();
    int cur = 0;
    for (int t = 0; t < 8; ++t){
        if (t+1 < 8) stage(cur^1, t+1);
        int r = w*16 + ls;
        s8v ah = *(const s8v*)&Ah[cur][r*32 + ((lg ^ (r&3)) << 3)];
        s8v al = *(const s8v*)&Al[cur][r*32 + ((lg ^ (r&3)) << 3)];
#pragma unroll
        for (int ct = 0; ct < 8; ++ct){
            int c = ct*16 + ls;
            s8v bh = *(const s8v*)&Bh[cur][c*32 + ((lg ^ (c&3)) << 3)];
            s8v bl = *(const s8v*)&Bl[cur][c*32 + ((lg ^ (c&3)) << 3)];
            acc[ct] = MFMA16(ah, bh, acc[ct]);
            acc[ct] = MFMA16(ah, bl, acc[ct]);
            acc[ct] = MFMA16(al, bh, acc[ct]);
        }
        __syncthreads();
        cur ^= 1;
    }
#pragma unroll
    for (int reg = 0; reg < 4; ++reg){
        int row = w*16 + lg*4 + reg;
        long long orow = rbase + row;
        int sI = sSrc[row], dI = sDst[row];
#pragma unroll
        for (int ct = 0; ct < 8; ++ct){
            int col = ct*16 + ls;
            w2out[orow*128 + col] = acc[ct][reg]
                                  + Q[(size_t)sI*256 + col]
                                  + Q[(size_t)dI*256 + 128 + col];
        }
    }
}

extern "C" void kernel_launch(void* const* d_in, const int* in_sizes, int n_in,
                              void* d_out, int out_size, void* d_ws, size_t ws_size,
                              hipStream_t stream){
    (void)in_sizes; (void)n_in; (void)out_size;
    const float* h       = (const float*)d_in[0];
    const float* edge_w  = (const float*)d_in[1];
    const float* W_node  = (const float*)d_in[2];
    const float* W_eedge = (const float*)d_in[3];
    const float* W_esf   = (const float*)d_in[4];
    const float* W_fuse  = (const float*)d_in[5];
    const float* b_fuse  = (const float*)d_in[6];
    const float* W_attn  = (const float*)d_in[7];
    const float* W_conc  = (const float*)d_in[8];
    const float* b_conc  = (const float*)d_in[9];
    const float* gamma   = (const float*)d_in[10];
    const float* beta    = (const float*)d_in[11];
    const float* W_aggre = (const float*)d_in[12];
    const int*   src     = (const int*)d_in[13];
    const int*   dst     = (const int*)d_in[14];

    float* out    = (float*)d_out;
    float* o_hout = out + OUT_HOUT;
    float* o_wout = out + OUT_WOUT;
    float* o_sat  = out + OUT_SAT;

    if (ws_size < (size_t)WS_FLOATS * 4) return;
    float* ws     = (float*)d_ws;
    unsigned short* w_owH = (unsigned short*)(ws + OFF_OW);
    unsigned short* w_owL = w_owH + (size_t)NE*128;   // = ws + 20,480,000 floats
    float* w_PQ   = ws + OFF_PQ;   // time-shared: P (kNG1->k2_mega), hagg (k5->k6), Q (kNG2->k7p)
    float* w_s    = ws + OFF_S;
    float* w_den  = ws + OFF_DEN;
    int*   w_cur  = (int*)(ws + OFF_CUR);
    unsigned short* w_wt = (unsigned short*)(ws + OFF_WT);
    float* w_C2   = ws + OFF_C2;

    unsigned* w_hnP = (unsigned*)o_wout;  // packed hn (free until k7p writes w_out)
    int* w_eidx = (int*)o_hout;           // pre-k6 scratch
    int* w_offs = w_eidx + NE;

    hipLaunchKernelGGL(kC2,       dim3(2), dim3(TB), 0, stream,
                       W_eedge, W_fuse + (size_t)256*128, w_C2);
    hipLaunchKernelGGL(kP2,       dim3(65536/TB), dim3(TB), 0, stream,
                       W_eedge, w_C2, W_aggre, w_wt, w_cur);
    hipLaunchKernelGGL(kB_count,  dim3(NE/TB), dim3(TB), 0, stream, dst, w_cur);
    hipLaunchKernelGGL(kC_scan,   dim3(1), dim3(TB), 0, stream, w_cur, w_offs);
    hipLaunchKernelGGL(kD_scatter,dim3(NE/TB), dim3(TB), 0, stream, dst, w_cur, w_eidx);
    hipLaunchKernelGGL(k1_hn,     dim3(NB), dim3(TB), 0, stream, h, W_node, w_hnP);
    hipLaunchKernelGGL(kNG,       dim3(2*NB), dim3(TB), 0, stream,
                       w_hnP, (const float*)nullptr, 1, W_fuse, w_PQ);          // P
    hipLaunchKernelGGL(k2_mega,   dim3(NE/64), dim3(TBM), 0, stream, edge_w,
                       w_wt + U_E2H, w_wt + U_E2L, W_esf, W_attn, b_fuse,
                       w_PQ, w_hnP, src, dst, w_owH, w_owL, o_sat, w_s);
    hipLaunchKernelGGL(k5_agg,    dim3(NN/4), dim3(TB), 0, stream, w_s, w_hnP, o_sat,
                       src, w_eidx, w_offs, w_cur, w_PQ, w_den);                // hagg
    hipLaunchKernelGGL(k6_conc,   dim3(NB), dim3(TB), 0, stream, w_PQ,
                       w_hnP, W_conc, b_conc, w_den, o_hout);
    hipLaunchKernelGGL(kNG,       dim3(2*NB), dim3(TB), 0, stream,
                       (const unsigned*)nullptr, o_hout, 0, W_aggre, w_PQ);     // Q
    hipLaunchKernelGGL(k7p,       dim3(NE/128), dim3(TBM), 0, stream,
                       w_owH, w_owL, w_s, o_sat, w_PQ, gamma, beta,
                       w_wt + U_A2H, w_wt + U_A2L, src, dst, o_wout);
}

// Round 10
// 726.059 us; speedup vs baseline: 1.0507x; 1.0507x over previous
//
#include <hip/hip_runtime.h>
#include <hip/hip_bf16.h>

#define TB 256
#define TBM 512   // MFMA kernels: 8 waves/block
#define BM 64
#define BK 32
#define BN 128
#define ASTR 68   // BM + 4 (fp32 path)
#define MAXD 160  // per-node edge cache for k5

static constexpr int NN = 20000;
static constexpr int NE = 320000;
static constexpr int NB = 313;    // ceil(NN/64)

// workspace layout (floats)
static constexpr long long OFF_OW  = 0;           // owH [0..20.48M), owL [20.48M..40.96M)
static constexpr long long OFF_HN  = 40960000;    // hnH/hnL: NN*128 ushorts each (2.56M floats)
static constexpr long long OFF_PQ  = 43520000;    // time-shared N*256: hagg (k5->k6) then Q (kNG->k7p)
static constexpr long long OFF_S   = 48640000;    // E
static constexpr long long OFF_DEN = 48960000;    // N
static constexpr long long OFF_CUR = 48980000;    // N ints
static constexpr long long OFF_WT  = 49000000;    // split weights: 196608 ushorts = 98304 floats
static constexpr long long WS_FLOATS = 49100000;  // ~196.4 MB (<= proven 196.6 MB budget)

// wt ushort offsets
static constexpr int U_EH = 0;       // We^T    [128 n][128 k] hi
static constexpr int U_EL = 16384;
static constexpr int U_FH = 32768;   // Wf^T    [128 n][384 k] hi
static constexpr int U_FL = 81920;
static constexpr int U_AH = 131072;  // Wa[256:512]^T [128 n][256 k'] hi
static constexpr int U_AL = 163840;

// d_out layout (floats)
static constexpr long long OUT_HOUT = 0;
static constexpr long long OUT_WOUT = 2560000;    // holds hnP until k7p writes w_out
static constexpr long long OUT_SAT  = 43520000;

typedef __attribute__((ext_vector_type(8))) short s8v;
typedef __attribute__((ext_vector_type(4))) float f32x4;
typedef __attribute__((ext_vector_type(8))) unsigned short u16x8;
typedef __attribute__((ext_vector_type(4))) unsigned short u16x4;

#define MFMA16(a,b,c) __builtin_amdgcn_mfma_f32_16x16x32_bf16(a,b,c,0,0,0)

__device__ __forceinline__ float lrelu(float x){ return x >= 0.f ? x : 0.1f*x; }

// async global->LDS, 16B per lane; LDS dest = wave-uniform base + lane*16
__device__ __forceinline__ void gl16(const void* g, void* l){
    __builtin_amdgcn_global_load_lds(
        (const __attribute__((address_space(1))) void*)g,
        (__attribute__((address_space(3))) void*)l, 16, 0, 0);
}

__device__ __forceinline__ void split1(float f, unsigned short& hi, unsigned short& lo){
    __hip_bfloat16 h = __float2bfloat16(f);
    float hf = __bfloat162float(h);
    __hip_bfloat16 l = __float2bfloat16(f - hf);
    hi = __builtin_bit_cast(unsigned short, h);
    lo = __builtin_bit_cast(unsigned short, l);
}
__device__ __forceinline__ void split8(float4 a, float4 b, s8v& hi, s8v& lo){
    float v[8] = {a.x,a.y,a.z,a.w,b.x,b.y,b.z,b.w};
#pragma unroll
    for (int j = 0; j < 8; ++j){
        unsigned short hs, ls;
        split1(v[j], hs, ls);
        hi[j] = (short)hs; lo[j] = (short)ls;
    }
}
// packed u32 (hi<<16|lo) -> fp32
__device__ __forceinline__ float bfp(unsigned p){
    return __uint_as_float(p & 0xffff0000u) + __uint_as_float(p << 16);
}

// LDS tile addressing: [128 rows][32 k] bf16; slot g holds k-group g^(row&3)
__device__ __forceinline__ int lds_a(int row, int g){
    return row*32 + ((g ^ (row & 3)) << 3);   // ushort index, 16B aligned
}

// ================= fp32 GEMM helpers =================
__device__ __forceinline__ void store_At(float (*Ast)[ASTR], int k4, int r, float4 v){
    Ast[k4+0][r] = v.x; Ast[k4+1][r] = v.y; Ast[k4+2][r] = v.z; Ast[k4+3][r] = v.w;
}
__device__ __forceinline__ void mm_chunk(const float (*Ast)[ASTR], const float (*Bs)[BN],
                                         int r0, int c0, float acc[4][8]){
#pragma unroll 4
    for (int k = 0; k < BK; ++k){
        const float4 av = *(const float4*)&Ast[k][r0];
        const float4 b0 = *(const float4*)&Bs[k][c0];
        const float4 b1 = *(const float4*)&Bs[k][64 + c0];
        const float a0=av.x, a1=av.y, a2=av.z, a3=av.w;
        const float b[8] = {b0.x,b0.y,b0.z,b0.w,b1.x,b1.y,b1.z,b1.w};
#pragma unroll
        for (int j = 0; j < 8; ++j){
            acc[0][j] = fmaf(a0, b[j], acc[0][j]);
            acc[1][j] = fmaf(a1, b[j], acc[1][j]);
            acc[2][j] = fmaf(a2, b[j], acc[2][j]);
            acc[3][j] = fmaf(a3, b[j], acc[3][j]);
        }
    }
}
__device__ __forceinline__ void load_B(const float* __restrict__ W, int kc,
                                       float (*Bs)[BN], int tid){
#pragma unroll
    for (int p = 0; p < 4; ++p){
        int idx = p*TB + tid;
        int row = idx >> 5;
        int c4  = (idx & 31) << 2;
        *(float4*)&Bs[row][c4] = *(const float4*)&W[(size_t)(kc+row)*BN + c4];
    }
}

// ---------------- k_prep: cur init + weight transpose/splits ----------------
__global__ __launch_bounds__(TB) void k_prep(const float* __restrict__ We,
                                             const float* __restrict__ Wf,
                                             const float* __restrict__ Wa,
                                             unsigned short* __restrict__ wt,
                                             int* __restrict__ cur){
    int id = blockIdx.x*TB + threadIdx.x;   // grid covers 98304
    if (id < NN) cur[id] = 0;
    unsigned short hs, ls;
    if (id < 16384){                        // We^T
        int n = id >> 7, k = id & 127;
        split1(We[(size_t)k*128 + n], hs, ls);
        wt[U_EH + id] = hs; wt[U_EL + id] = ls;
    } else if (id < 65536){                 // Wf^T (K=384)
        int local = id - 16384;
        int n = local / 384, k = local - n*384;
        split1(Wf[(size_t)k*128 + n], hs, ls);
        wt[U_FH + local] = hs; wt[U_FL + local] = ls;
    } else if (id < 98304){                 // Wa[256:512]^T (K'=256)
        int local = id - 65536;
        int n = local >> 8, kk = local & 255;
        split1(Wa[(size_t)(256+kk)*128 + n], hs, ls);
        wt[U_AH + local] = hs; wt[U_AL + local] = ls;
    }
}

// ---------------- sort pipeline ----------------
__global__ __launch_bounds__(TB) void kB_count(const int* __restrict__ dst,
                                               int* __restrict__ cur){
    int e = blockIdx.x*TB + threadIdx.x;
    atomicAdd(&cur[dst[e]], 1);
}
__global__ __launch_bounds__(TB) void kC_scan(int* __restrict__ cur,
                                              int* __restrict__ offs){
    __shared__ int part[TB];
    __shared__ int spre[TB];
    const int tid = threadIdx.x;
    const int CH = (NN + TB - 1) / TB;
    const int base = tid * CH;
    int sum = 0;
    for (int i = 0; i < CH; ++i){ int idx = base + i; if (idx < NN) sum += cur[idx]; }
    part[tid] = sum;
    __syncthreads();
    if (tid == 0){ int r = 0; for (int i = 0; i < TB; ++i){ spre[i] = r; r += part[i]; } }
    __syncthreads();
    int run = spre[tid];
    for (int i = 0; i < CH; ++i){
        int idx = base + i;
        if (idx < NN){ int c = cur[idx]; offs[idx] = run; cur[idx] = run; run += c; }
    }
}
__global__ __launch_bounds__(TB) void kD_scatter(const int* __restrict__ dst,
                                                 int* __restrict__ cur,
                                                 int* __restrict__ eidx){
    int e = blockIdx.x*TB + threadIdx.x;
    int p = atomicAdd(&cur[dst[e]], 1);
    eidx[p] = e;
}

// ---------------- k1: hn = h @ W_node (fp32 GEMM; outputs hnH/hnL split + hnP packed) ----------------
__global__ __launch_bounds__(TB) void k1_hn(const float* __restrict__ h,
                                            const float* __restrict__ Wn,
                                            unsigned short* __restrict__ hnH,
                                            unsigned short* __restrict__ hnL,
                                            unsigned* __restrict__ hnP){
    __shared__ float Ast[BK][ASTR];
    __shared__ float Bs[BK][BN];
    const int tid = threadIdx.x;
    const int rbase = blockIdx.x * BM;
    const int tc = tid & 15, tr = tid >> 4;
    const int r0 = tr*4, c0 = tc*4;
    float acc[4][8] = {};
    for (int kc = 0; kc < 128; kc += BK){
        __syncthreads();
        {
            int lr = tid >> 3, k4 = (tid & 7) << 2;
#pragma unroll
            for (int p = 0; p < 2; ++p){
                int r = p*32 + lr;
                int rr = rbase + r; if (rr >= NN) rr = NN-1;
                float4 v = *(const float4*)&h[(size_t)rr*128 + kc + k4];
                store_At(Ast, k4, r, v);
            }
        }
        load_B(Wn, kc, Bs, tid);
        __syncthreads();
        mm_chunk(Ast, Bs, r0, c0, acc);
    }
#pragma unroll
    for (int i = 0; i < 4; ++i){
        int rr = rbase + r0 + i;
        if (rr < NN){
            u16x4 h0, l0, h1, l1;
            uint4 p0, p1;
#pragma unroll
            for (int j = 0; j < 4; ++j){
                unsigned short hs, ls;
                split1(acc[i][j], hs, ls);
                h0[j] = hs; l0[j] = ls;
                ((unsigned*)&p0)[j] = ((unsigned)hs << 16) | ls;
                split1(acc[i][4+j], hs, ls);
                h1[j] = hs; l1[j] = ls;
                ((unsigned*)&p1)[j] = ((unsigned)hs << 16) | ls;
            }
            *(u16x4*)&hnH[(size_t)rr*128 + c0] = h0;
            *(u16x4*)&hnL[(size_t)rr*128 + c0] = l0;
            *(u16x4*)&hnH[(size_t)rr*128 + 64 + c0] = h1;
            *(u16x4*)&hnL[(size_t)rr*128 + 64 + c0] = l1;
            *(uint4*)&hnP[(size_t)rr*128 + c0] = p0;
            *(uint4*)&hnP[(size_t)rr*128 + 64 + c0] = p1;
        }
    }
}

// ================== MFMA split-bf16 edge GEMMs: 512 thr, 8 waves, 128x128 tile ==================

// ---------------- k2: ow = edge_w @ W_eedge ; w1 = (lrelu(ow)@W_esf)*ow ----------------
__global__ __launch_bounds__(TBM) void k2_mfma(const float* __restrict__ ew,
                                               const unsigned short* __restrict__ wtH,
                                               const unsigned short* __restrict__ wtL,
                                               const float* __restrict__ Wesf,
                                               unsigned short* __restrict__ owH,
                                               unsigned short* __restrict__ owL,
                                               float* __restrict__ sat){
    __shared__ __align__(16) unsigned short Ah[2][4096], Al[2][4096], Bh[2][4096], Bl[2][4096];
    __shared__ float sEsf[128];
    const int tid = threadIdx.x;
    const long long rbase = (long long)blockIdx.x * 128;
    const int lane = tid & 63, w = tid >> 6;
    const int ls = lane & 15, lg = lane >> 4;
    const int srow = tid >> 2, sg = tid & 3;
    const int gsw = sg ^ (srow & 3);
    const int aslot = srow*32 + (gsw << 3);
    if (tid < 128) sEsf[tid] = Wesf[tid];
    f32x4 acc[8] = {};
    auto stage = [&](int nb, int t){
        const int kc = t*32;
        gl16(&wtH[srow*128 + kc + gsw*8], &Bh[nb][w*512]);
        gl16(&wtL[srow*128 + kc + gsw*8], &Bl[nb][w*512]);
        const float* p = &ew[(rbase + srow)*128 + kc + sg*8];
        float4 v0 = *(const float4*)p, v1 = *(const float4*)(p+4);
        s8v hi, lo; split8(v0, v1, hi, lo);
        *(s8v*)&Ah[nb][aslot] = hi; *(s8v*)&Al[nb][aslot] = lo;
    };
    stage(0, 0);
    __syncthreads();
    int cur = 0;
    for (int t = 0; t < 4; ++t){
        if (t+1 < 4) stage(cur^1, t+1);
        s8v ah = *(const s8v*)&Ah[cur][lds_a(w*16 + ls, lg)];
        s8v al = *(const s8v*)&Al[cur][lds_a(w*16 + ls, lg)];
#pragma unroll
        for (int ct = 0; ct < 8; ++ct){
            int c = ct*16 + ls;
            s8v bh = *(const s8v*)&Bh[cur][lds_a(c,lg)];
            s8v bl = *(const s8v*)&Bl[cur][lds_a(c,lg)];
            acc[ct] = MFMA16(ah, bh, acc[ct]);
            acc[ct] = MFMA16(ah, bl, acc[ct]);
            acc[ct] = MFMA16(al, bh, acc[ct]);
        }
        __syncthreads();
        cur ^= 1;
    }
#pragma unroll
    for (int reg = 0; reg < 4; ++reg){
        float p = 0.f;
#pragma unroll
        for (int ct = 0; ct < 8; ++ct)
            p += lrelu(acc[ct][reg]) * sEsf[ct*16 + ls];
#pragma unroll
        for (int m = 1; m < 16; m <<= 1) p += __shfl_xor(p, m);
        long long orow = rbase + w*16 + lg*4 + reg;
#pragma unroll
        for (int ct = 0; ct < 8; ++ct){
            float o = acc[ct][reg];
            int col = ct*16 + ls;
            sat[orow*384 + 256 + col] = p * o;
            unsigned short hs_, ls_; split1(o, hs_, ls_);
            owH[orow*128 + col] = hs_;
            owL[orow*128 + col] = ls_;
        }
    }
}

// ---------------- k3: sat build + inw GEMM + attn dot -> s ----------------
__global__ __launch_bounds__(TBM) void k3_mfma(const unsigned short* __restrict__ hnH,
                                               const unsigned short* __restrict__ hnL,
                                               const unsigned* __restrict__ hnP,
                                               const unsigned short* __restrict__ wtH,
                                               const unsigned short* __restrict__ wtL,
                                               const float* __restrict__ bf,
                                               const float* __restrict__ Wattn,
                                               const int* __restrict__ src,
                                               const int* __restrict__ dst,
                                               float* __restrict__ sat,
                                               float* __restrict__ s_ws){
    __shared__ __align__(16) unsigned short Ah[2][4096], Al[2][4096], Bh[2][4096], Bl[2][4096];
    __shared__ float sBf[128], sAtt[128];
    __shared__ int sSrc[128], sDst[128];
    const int tid = threadIdx.x;
    const long long rbase = (long long)blockIdx.x * 128;
    const int lane = tid & 63, w = tid >> 6;
    const int ls = lane & 15, lg = lane >> 4;
    const int srow = tid >> 2, sg = tid & 3;
    const int gsw = sg ^ (srow & 3);
    const int aslot = srow*32 + (gsw << 3);
    if (tid < 128){
        sBf[tid] = bf[tid]; sAtt[tid] = Wattn[tid];
        sSrc[tid] = src[rbase + tid]; sDst[tid] = dst[rbase + tid];
    }
    __syncthreads();   // sSrc/sDst used by stage
    f32x4 acc[8] = {};
    auto stage = [&](int nb, int t){
        const int kc = t*32;
        gl16(&wtH[srow*384 + kc + gsw*8], &Bh[nb][w*512]);
        gl16(&wtL[srow*384 + kc + gsw*8], &Bl[nb][w*512]);
        long long e = rbase + srow;
        if (kc < 256){
            int node = (kc < 128) ? sSrc[srow] : sDst[srow];
            int col0 = kc & 127;
            gl16(&hnH[(size_t)node*128 + col0 + gsw*8], &Ah[nb][w*512]);
            gl16(&hnL[(size_t)node*128 + col0 + gsw*8], &Al[nb][w*512]);
            // reconstruct fp32 for the sat output write (natural k-group)
            const unsigned* pp = &hnP[(size_t)node*128 + col0 + sg*8];
            uint4 q0 = *(const uint4*)pp, q1 = *(const uint4*)(pp+4);
            float4 v0 = {bfp(q0.x), bfp(q0.y), bfp(q0.z), bfp(q0.w)};
            float4 v1 = {bfp(q1.x), bfp(q1.y), bfp(q1.z), bfp(q1.w)};
            *(float4*)&sat[e*384 + kc + sg*8] = v0;
            *(float4*)&sat[e*384 + kc + sg*8 + 4] = v1;
        } else {
            const float* p = &sat[e*384 + kc + sg*8];   // w1 fp32 (written by k2)
            float4 v0 = *(const float4*)p, v1 = *(const float4*)(p+4);
            s8v hi, lo; split8(v0, v1, hi, lo);
            *(s8v*)&Ah[nb][aslot] = hi; *(s8v*)&Al[nb][aslot] = lo;
        }
    };
    stage(0, 0);
    __syncthreads();
    int cur = 0;
    for (int t = 0; t < 12; ++t){
        if (t+1 < 12) stage(cur^1, t+1);
        s8v ah = *(const s8v*)&Ah[cur][lds_a(w*16 + ls, lg)];
        s8v al = *(const s8v*)&Al[cur][lds_a(w*16 + ls, lg)];
#pragma unroll
        for (int ct = 0; ct < 8; ++ct){
            int c = ct*16 + ls;
            s8v bh = *(const s8v*)&Bh[cur][lds_a(c,lg)];
            s8v bl = *(const s8v*)&Bl[cur][lds_a(c,lg)];
            acc[ct] = MFMA16(ah, bh, acc[ct]);
            acc[ct] = MFMA16(ah, bl, acc[ct]);
            acc[ct] = MFMA16(al, bh, acc[ct]);
        }
        __syncthreads();
        cur ^= 1;
    }
    // epilogue: attn dot -> s only
#pragma unroll
    for (int reg = 0; reg < 4; ++reg){
        float p = 0.f;
#pragma unroll
        for (int ct = 0; ct < 8; ++ct){
            int col = ct*16 + ls;
            p += lrelu(acc[ct][reg] + sBf[col]) * sAtt[col];
        }
#pragma unroll
        for (int m = 1; m < 16; m <<= 1) p += __shfl_xor(p, m);
        if (ls == 0) s_ws[rbase + w*16 + lg*4 + reg] = p;
    }
}

// ---------------- k5: wave-per-node softmax + gather-aggregate ----------------
__global__ __launch_bounds__(TB) void k5_agg(const float* __restrict__ s,
                                             const unsigned* __restrict__ hnP,
                                             const float* __restrict__ sat,
                                             const int* __restrict__ src,
                                             const int* __restrict__ eidx,
                                             const int* __restrict__ offs,
                                             const int* __restrict__ cur,
                                             float* __restrict__ hagg,
                                             float* __restrict__ den){
    __shared__ int   sEu[4][MAXD];
    __shared__ int   sEs[4][MAXD];
    __shared__ float sAl[4][MAXD];
    __shared__ float sWc[4][MAXD];
    const int wv = threadIdx.x >> 6, lane = threadIdx.x & 63;
    const int n = blockIdx.x*4 + wv;
    int* Eu = sEu[wv]; int* Es = sEs[wv];
    float* Al = sAl[wv]; float* Wc = sWc[wv];
    const int start = offs[n];
    const int deg = cur[n] - start;
    const int dc = deg < MAXD ? deg : MAXD;
    for (int i = lane; i < dc; i += 64) Eu[i] = eidx[start+i];
    __syncthreads();
    for (int i = lane; i < dc; i += 64){
        int my = Eu[i], r = 0;
        for (int j = 0; j < dc; ++j) r += (Eu[j] < my);
        Es[r] = my;
    }
    __syncthreads();
    float lm = -3.402823466e38f;
    for (int i = lane; i < dc; i += 64){
        int e = Es[i];
        float sv = s[e];
        Wc[i] = sv;
        Eu[i] = src[e];
        lm = fmaxf(lm, sv);
    }
    for (int i = MAXD + lane; i < deg; i += 64) lm = fmaxf(lm, s[eidx[start+i]]);
#pragma unroll
    for (int m2 = 32; m2; m2 >>= 1) lm = fmaxf(lm, __shfl_xor(lm, m2));
    const float m = lm;
    float lsum = 0.f;
    for (int i = lane; i < dc; i += 64){
        float ev = expf(Wc[i] - m);
        Al[i] = ev;
        lsum += ev;
    }
    for (int i = MAXD + lane; i < deg; i += 64) lsum += expf(s[eidx[start+i]] - m);
#pragma unroll
    for (int m2 = 32; m2; m2 >>= 1) lsum += __shfl_xor(lsum, m2);
    const float denom = lsum;
    const float inv = (deg > 0) ? 1.f/denom : 0.f;
    for (int i = lane; i < dc; i += 64){
        float al = Al[i] * inv;
        Al[i] = al;
        Wc[i] = al * Wc[i];
    }
    __syncthreads();
    float a0=0.f, a1=0.f, a2=0.f, a3=0.f;
    for (int i = 0; i < dc; ++i){
        int sI = Eu[i];
        size_t e = (size_t)Es[i];
        float al = Al[i], wc = Wc[i];
        unsigned p0 = hnP[(size_t)sI*128 + lane];
        unsigned p1 = hnP[(size_t)sI*128 + 64 + lane];
        float w0 = sat[e*384 + 256 + lane];
        float w1v = sat[e*384 + 256 + 64 + lane];
        a0 = fmaf(al, bfp(p0), a0);
        a1 = fmaf(al, bfp(p1), a1);
        a2 = fmaf(wc, w0, a2);
        a3 = fmaf(wc, w1v, a3);
    }
    for (int i = MAXD; i < deg; ++i){
        int e = eidx[start+i];
        float sv = s[e];
        float al = expf(sv - m) * inv;
        float wc = al * sv;
        int sI = src[e];
        a0 = fmaf(al, bfp(hnP[(size_t)sI*128 + lane]), a0);
        a1 = fmaf(al, bfp(hnP[(size_t)sI*128 + 64 + lane]), a1);
        a2 = fmaf(wc, sat[(size_t)e*384 + 256 + lane], a2);
        a3 = fmaf(wc, sat[(size_t)e*384 + 256 + 64 + lane], a3);
    }
    const size_t b = (size_t)n*256;
    hagg[b + lane] = a0;
    hagg[b + 64 + lane] = a1;
    hagg[b + 128 + lane] = a2;
    hagg[b + 192 + lane] = a3;
    if (lane == 0) den[n] = (deg > 0) ? denom : 0.f;
}

// ---------------- k6: h_new = [h_agg, hn] @ W_conc + b_conc ; indeg select ----------------
__global__ __launch_bounds__(TB) void k6_conc(const float* __restrict__ hagg,
                                              const unsigned* __restrict__ hnP,
                                              const float* __restrict__ Wc,
                                              const float* __restrict__ bc,
                                              const float* __restrict__ den,
                                              float* __restrict__ hout){
    __shared__ float Ast[BK][ASTR];
    __shared__ float Bs[BK][BN];
    __shared__ float sBc[BN];
    const int tid = threadIdx.x;
    const int rbase = blockIdx.x * BM;
    const int tc = tid & 15, tr = tid >> 4;
    const int r0 = tr*4, c0 = tc*4;
    if (tid < BN) sBc[tid] = bc[tid];
    float acc[4][8] = {};
    for (int chunk = 0; chunk < 12; ++chunk){
        int kc = chunk * BK;
        __syncthreads();
        {
            int lr = tid >> 3, k4 = (tid & 7) << 2;
#pragma unroll
            for (int p = 0; p < 2; ++p){
                int r = p*32 + lr;
                int rr = rbase + r; if (rr >= NN) rr = NN-1;
                float4 v;
                if (chunk < 8) v = *(const float4*)&hagg[(size_t)rr*256 + kc + k4];
                else {
                    int cb = (kc - 256) + k4;
                    uint4 q = *(const uint4*)&hnP[(size_t)rr*128 + cb];
                    v.x = bfp(q.x); v.y = bfp(q.y); v.z = bfp(q.z); v.w = bfp(q.w);
                }
                store_At(Ast, k4, r, v);
            }
        }
        load_B(Wc, kc, Bs, tid);
        __syncthreads();
        mm_chunk(Ast, Bs, r0, c0, acc);
    }
#pragma unroll
    for (int i = 0; i < 4; ++i){
        int rr = rbase + r0 + i;
        if (rr >= NN) continue;
        bool keep = den[rr] > 0.f;
        float o[8];
#pragma unroll
        for (int j = 0; j < 8; ++j){
            int col = (j < 4) ? (c0 + j) : (60 + c0 + j);
            float fb = bfp(hnP[(size_t)rr*128 + col]);
            o[j] = keep ? acc[i][j] + sBc[col] : fb;
        }
        float4 o0 = {o[0],o[1],o[2],o[3]}, o1 = {o[4],o[5],o[6],o[7]};
        *(float4*)&hout[(size_t)rr*128 + c0] = o0;
        *(float4*)&hout[(size_t)rr*128 + 64 + c0] = o1;
    }
}

// ---------------- kNG: Q[n][half*128..+128] = hout @ Wa_half (fp32) ----------------
__global__ __launch_bounds__(TB) void kNG(const float* __restrict__ aF,
                                          const float* __restrict__ W,   // [>=256][128] rows
                                          float* __restrict__ O){        // [N][256]
    __shared__ float Ast[BK][ASTR];
    __shared__ float Bs[BK][BN];
    const int tid = threadIdx.x;
    const int half = blockIdx.x >= NB ? 1 : 0;
    const int rbase = (blockIdx.x - half*NB) * BM;
    const float* Wp = W + (size_t)half*16384;
    const int tc = tid & 15, tr = tid >> 4;
    const int r0 = tr*4, c0 = tc*4;
    float acc[4][8] = {};
    for (int kc = 0; kc < 128; kc += BK){
        __syncthreads();
        {
            int lr = tid >> 3, k4 = (tid & 7) << 2;
#pragma unroll
            for (int p = 0; p < 2; ++p){
                int r = p*32 + lr;
                int rr = rbase + r; if (rr >= NN) rr = NN-1;
                float4 v = *(const float4*)&aF[(size_t)rr*128 + kc + k4];
                store_At(Ast, k4, r, v);
            }
        }
        load_B(Wp, kc, Bs, tid);
        __syncthreads();
        mm_chunk(Ast, Bs, r0, c0, acc);
    }
#pragma unroll
    for (int i = 0; i < 4; ++i){
        int rr = rbase + r0 + i;
        if (rr < NN){
            float4 o0 = {acc[i][0],acc[i][1],acc[i][2],acc[i][3]};
            float4 o1 = {acc[i][4],acc[i][5],acc[i][6],acc[i][7]};
            *(float4*)&O[(size_t)rr*256 + half*128 + c0] = o0;
            *(float4*)&O[(size_t)rr*256 + half*128 + 64 + c0] = o1;
        }
    }
}

// ---------------- k7p: w_out = [w_bn, ow] @ Wa[256:512] + Q1[src] + Q2[dst] ----------------
__global__ __launch_bounds__(TBM) void k7p(const unsigned short* __restrict__ owH,
                                           const unsigned short* __restrict__ owL,
                                           const float* __restrict__ sarr,
                                           const float* __restrict__ sat,
                                           const float* __restrict__ Q,
                                           const float* __restrict__ gamma,
                                           const float* __restrict__ beta,
                                           const unsigned short* __restrict__ wtH,  // [128][256]
                                           const unsigned short* __restrict__ wtL,
                                           const int* __restrict__ src,
                                           const int* __restrict__ dst,
                                           float* __restrict__ w2out){
    __shared__ __align__(16) unsigned short Ah[2][4096], Al[2][4096], Bh[2][4096], Bl[2][4096];
    __shared__ float sGam[128], sBet[128], sS[128];
    __shared__ int sSrc[128], sDst[128];
    const int tid = threadIdx.x;
    const long long rbase = (long long)blockIdx.x * 128;
    const int lane = tid & 63, w = tid >> 6;
    const int ls = lane & 15, lg = lane >> 4;
    const int srow = tid >> 2, sg = tid & 3;
    const int gsw = sg ^ (srow & 3);
    const int aslot = srow*32 + (gsw << 3);
    const float ISR = 0.9999950000374997f;  // 1/sqrt(1+1e-5)
    if (tid < 128){
        sGam[tid] = gamma[tid] * ISR; sBet[tid] = beta[tid];
        sSrc[tid] = src[rbase + tid]; sDst[tid] = dst[rbase + tid];
        sS[tid] = sarr[rbase + tid];
    }
    __syncthreads();
    f32x4 acc[8] = {};
    auto stage = [&](int nb, int t){
        const int kc = t*32;
        gl16(&wtH[srow*256 + kc + gsw*8], &Bh[nb][w*512]);
        gl16(&wtL[srow*256 + kc + gsw*8], &Bl[nb][w*512]);
        long long e = rbase + srow;
        if (kc < 128){
            int cb = kc + sg*8;
            float se = sS[srow];
            const float* p = &sat[e*384 + 256 + cb];   // w1
            float4 v0 = *(const float4*)p, v1 = *(const float4*)(p+4);
            v0.x = fmaf(v0.x*se, sGam[cb+0], sBet[cb+0]);
            v0.y = fmaf(v0.y*se, sGam[cb+1], sBet[cb+1]);
            v0.z = fmaf(v0.z*se, sGam[cb+2], sBet[cb+2]);
            v0.w = fmaf(v0.w*se, sGam[cb+3], sBet[cb+3]);
            v1.x = fmaf(v1.x*se, sGam[cb+4], sBet[cb+4]);
            v1.y = fmaf(v1.y*se, sGam[cb+5], sBet[cb+5]);
            v1.z = fmaf(v1.z*se, sGam[cb+6], sBet[cb+6]);
            v1.w = fmaf(v1.w*se, sGam[cb+7], sBet[cb+7]);
            s8v hi, lo; split8(v0, v1, hi, lo);
            *(s8v*)&Ah[nb][aslot] = hi; *(s8v*)&Al[nb][aslot] = lo;
        } else {
            int col0 = kc - 128;
            gl16(&owH[e*128 + col0 + gsw*8], &Ah[nb][w*512]);
            gl16(&owL[e*128 + col0 + gsw*8], &Al[nb][w*512]);
        }
    };
    stage(0, 0);
    __syncthreads();
    int cur = 0;
    for (int t = 0; t < 8; ++t){
        if (t+1 < 8) stage(cur^1, t+1);
        int r = w*16 + ls;
        s8v ah = *(const s8v*)&Ah[cur][r*32 + ((lg ^ (r&3)) << 3)];
        s8v al = *(const s8v*)&Al[cur][r*32 + ((lg ^ (r&3)) << 3)];
#pragma unroll
        for (int ct = 0; ct < 8; ++ct){
            int c = ct*16 + ls;
            s8v bh = *(const s8v*)&Bh[cur][c*32 + ((lg ^ (c&3)) << 3)];
            s8v bl = *(const s8v*)&Bl[cur][c*32 + ((lg ^ (c&3)) << 3)];
            acc[ct] = MFMA16(ah, bh, acc[ct]);
            acc[ct] = MFMA16(ah, bl, acc[ct]);
            acc[ct] = MFMA16(al, bh, acc[ct]);
        }
        __syncthreads();
        cur ^= 1;
    }
#pragma unroll
    for (int reg = 0; reg < 4; ++reg){
        int row = w*16 + lg*4 + reg;
        long long orow = rbase + row;
        int sI = sSrc[row], dI = sDst[row];
#pragma unroll
        for (int ct = 0; ct < 8; ++ct){
            int col = ct*16 + ls;
            w2out[orow*128 + col] = acc[ct][reg]
                                  + Q[(size_t)sI*256 + col]
                                  + Q[(size_t)dI*256 + 128 + col];
        }
    }
}

extern "C" void kernel_launch(void* const* d_in, const int* in_sizes, int n_in,
                              void* d_out, int out_size, void* d_ws, size_t ws_size,
                              hipStream_t stream){
    (void)in_sizes; (void)n_in; (void)out_size;
    const float* h       = (const float*)d_in[0];
    const float* edge_w  = (const float*)d_in[1];
    const float* W_node  = (const float*)d_in[2];
    const float* W_eedge = (const float*)d_in[3];
    const float* W_esf   = (const float*)d_in[4];
    const float* W_fuse  = (const float*)d_in[5];
    const float* b_fuse  = (const float*)d_in[6];
    const float* W_attn  = (const float*)d_in[7];
    const float* W_conc  = (const float*)d_in[8];
    const float* b_conc  = (const float*)d_in[9];
    const float* gamma   = (const float*)d_in[10];
    const float* beta    = (const float*)d_in[11];
    const float* W_aggre = (const float*)d_in[12];
    const int*   src     = (const int*)d_in[13];
    const int*   dst     = (const int*)d_in[14];

    float* out    = (float*)d_out;
    float* o_hout = out + OUT_HOUT;
    float* o_wout = out + OUT_WOUT;
    float* o_sat  = out + OUT_SAT;

    if (ws_size < (size_t)WS_FLOATS * 4) return;
    float* ws     = (float*)d_ws;
    unsigned short* w_owH = (unsigned short*)(ws + OFF_OW);
    unsigned short* w_owL = w_owH + (size_t)NE*128;     // float offset 20.48M
    unsigned short* w_hnH = (unsigned short*)(ws + OFF_HN);
    unsigned short* w_hnL = w_hnH + (size_t)NN*128;
    float* w_PQ   = ws + OFF_PQ;   // time-shared: hagg (k5->k6) then Q (kNG->k7p)
    float* w_s    = ws + OFF_S;
    float* w_den  = ws + OFF_DEN;
    int*   w_cur  = (int*)(ws + OFF_CUR);
    unsigned short* w_wt = (unsigned short*)(ws + OFF_WT);

    unsigned* w_hnP = (unsigned*)o_wout;  // packed hn (free until k7p writes w_out)
    int* w_eidx = (int*)o_hout;           // pre-k6 scratch
    int* w_offs = w_eidx + NE;

    hipLaunchKernelGGL(k_prep,    dim3(98304/TB), dim3(TB), 0, stream,
                       W_eedge, W_fuse, W_aggre, w_wt, w_cur);
    hipLaunchKernelGGL(kB_count,  dim3(NE/TB), dim3(TB), 0, stream, dst, w_cur);
    hipLaunchKernelGGL(kC_scan,   dim3(1), dim3(TB), 0, stream, w_cur, w_offs);
    hipLaunchKernelGGL(kD_scatter,dim3(NE/TB), dim3(TB), 0, stream, dst, w_cur, w_eidx);
    hipLaunchKernelGGL(k1_hn,     dim3(NB), dim3(TB), 0, stream, h, W_node,
                       w_hnH, w_hnL, w_hnP);
    hipLaunchKernelGGL(k2_mfma,   dim3(NE/128), dim3(TBM), 0, stream, edge_w,
                       w_wt + U_EH, w_wt + U_EL, W_esf, w_owH, w_owL, o_sat);
    hipLaunchKernelGGL(k3_mfma,   dim3(NE/128), dim3(TBM), 0, stream, w_hnH, w_hnL, w_hnP,
                       w_wt + U_FH, w_wt + U_FL, b_fuse, W_attn,
                       src, dst, o_sat, w_s);
    hipLaunchKernelGGL(k5_agg,    dim3(NN/4), dim3(TB), 0, stream, w_s, w_hnP, o_sat,
                       src, w_eidx, w_offs, w_cur, w_PQ, w_den);
    hipLaunchKernelGGL(k6_conc,   dim3(NB), dim3(TB), 0, stream, w_PQ,
                       w_hnP, W_conc, b_conc, w_den, o_hout);
    hipLaunchKernelGGL(kNG,       dim3(2*NB), dim3(TB), 0, stream, o_hout, W_aggre, w_PQ);
    hipLaunchKernelGGL(k7p,       dim3(NE/128), dim3(TBM), 0, stream,
                       w_owH, w_owL, w_s, o_sat, w_PQ, gamma, beta,
                       w_wt + U_AH, w_wt + U_AL, src, dst, o_wout);
}

// Round 11
// 698.919 us; speedup vs baseline: 1.0915x; 1.0388x over previous
//
#include <hip/hip_runtime.h>
#include <hip/hip_bf16.h>

#define TB 256
#define TBM 512   // MFMA kernels: 8 waves/block
#define BM 64
#define BK 32
#define BN 128
#define ASTR 68   // BM + 4 (fp32 path)
#define MAXD 160  // per-node edge cache for k5

static constexpr int NN = 20000;
static constexpr int NE = 320000;
static constexpr int NB = 313;    // ceil(NN/64)

// workspace layout (floats)
static constexpr long long OFF_OW  = 0;           // owH [0..20.48M), owL [20.48M..40.96M)
static constexpr long long OFF_HN  = 40960000;    // hnH/hnL: NN*128 ushorts each (2.56M floats)
static constexpr long long OFF_PQ  = 43520000;    // time-shared N*256: hagg (k5->k6) then Q (kNG->k7p)
static constexpr long long OFF_S   = 48640000;    // E
static constexpr long long OFF_DEN = 48960000;    // N
static constexpr long long OFF_CUR = 48980000;    // N ints
static constexpr long long OFF_WT  = 49000000;    // split weights: 196608 ushorts = 98304 floats
static constexpr long long WS_FLOATS = 49100000;  // ~196.4 MB (<= proven budget)

// wt ushort offsets
static constexpr int U_EH = 0;       // We^T    [128 n][128 k] hi
static constexpr int U_EL = 16384;
static constexpr int U_FH = 32768;   // Wf^T    [128 n][384 k] hi
static constexpr int U_FL = 81920;
static constexpr int U_AH = 131072;  // Wa[256:512]^T [128 n][256 k'] hi
static constexpr int U_AL = 163840;

// d_out layout (floats)
static constexpr long long OUT_HOUT = 0;
static constexpr long long OUT_WOUT = 2560000;    // holds hnP until k7p writes w_out
static constexpr long long OUT_SAT  = 43520000;

typedef __attribute__((ext_vector_type(8))) short s8v;
typedef __attribute__((ext_vector_type(4))) float f32x4;
typedef __attribute__((ext_vector_type(4))) unsigned short u16x4;

#define MFMA16(a,b,c) __builtin_amdgcn_mfma_f32_16x16x32_bf16(a,b,c,0,0,0)

__device__ __forceinline__ float lrelu(float x){ return x >= 0.f ? x : 0.1f*x; }

// wave-local LDS sync (per-wave-private buffers only; LDS is in-order per wave)
__device__ __forceinline__ void wsync(){ asm volatile("s_waitcnt lgkmcnt(0)" ::: "memory"); }

// async global->LDS, 16B per lane; LDS dest = wave-uniform base + lane*16
__device__ __forceinline__ void gl16(const void* g, void* l){
    __builtin_amdgcn_global_load_lds(
        (const __attribute__((address_space(1))) void*)g,
        (__attribute__((address_space(3))) void*)l, 16, 0, 0);
}

__device__ __forceinline__ void split1(float f, unsigned short& hi, unsigned short& lo){
    __hip_bfloat16 h = __float2bfloat16(f);
    float hf = __bfloat162float(h);
    __hip_bfloat16 l = __float2bfloat16(f - hf);
    hi = __builtin_bit_cast(unsigned short, h);
    lo = __builtin_bit_cast(unsigned short, l);
}
__device__ __forceinline__ void split8(float4 a, float4 b, s8v& hi, s8v& lo){
    float v[8] = {a.x,a.y,a.z,a.w,b.x,b.y,b.z,b.w};
#pragma unroll
    for (int j = 0; j < 8; ++j){
        unsigned short hs, ls;
        split1(v[j], hs, ls);
        hi[j] = (short)hs; lo[j] = (short)ls;
    }
}
// packed u32 (hi<<16|lo) -> fp32
__device__ __forceinline__ float bfp(unsigned p){
    return __uint_as_float(p & 0xffff0000u) + __uint_as_float(p << 16);
}

// LDS tile addressing: [128 rows][32 k] bf16; slot g holds k-group g^(row&3)
__device__ __forceinline__ int lds_a(int row, int g){
    return row*32 + ((g ^ (row & 3)) << 3);   // ushort index, 16B aligned
}

// ================= fp32 GEMM helpers =================
__device__ __forceinline__ void store_At(float (*Ast)[ASTR], int k4, int r, float4 v){
    Ast[k4+0][r] = v.x; Ast[k4+1][r] = v.y; Ast[k4+2][r] = v.z; Ast[k4+3][r] = v.w;
}
__device__ __forceinline__ void mm_chunk(const float (*Ast)[ASTR], const float (*Bs)[BN],
                                         int r0, int c0, float acc[4][8]){
#pragma unroll 4
    for (int k = 0; k < BK; ++k){
        const float4 av = *(const float4*)&Ast[k][r0];
        const float4 b0 = *(const float4*)&Bs[k][c0];
        const float4 b1 = *(const float4*)&Bs[k][64 + c0];
        const float a0=av.x, a1=av.y, a2=av.z, a3=av.w;
        const float b[8] = {b0.x,b0.y,b0.z,b0.w,b1.x,b1.y,b1.z,b1.w};
#pragma unroll
        for (int j = 0; j < 8; ++j){
            acc[0][j] = fmaf(a0, b[j], acc[0][j]);
            acc[1][j] = fmaf(a1, b[j], acc[1][j]);
            acc[2][j] = fmaf(a2, b[j], acc[2][j]);
            acc[3][j] = fmaf(a3, b[j], acc[3][j]);
        }
    }
}
__device__ __forceinline__ void load_B(const float* __restrict__ W, int kc,
                                       float (*Bs)[BN], int tid){
#pragma unroll
    for (int p = 0; p < 4; ++p){
        int idx = p*TB + tid;
        int row = idx >> 5;
        int c4  = (idx & 31) << 2;
        *(float4*)&Bs[row][c4] = *(const float4*)&W[(size_t)(kc+row)*BN + c4];
    }
}

// ---------------- k_prep: cur init + weight transpose/splits ----------------
__global__ __launch_bounds__(TB) void k_prep(const float* __restrict__ We,
                                             const float* __restrict__ Wf,
                                             const float* __restrict__ Wa,
                                             unsigned short* __restrict__ wt,
                                             int* __restrict__ cur){
    int id = blockIdx.x*TB + threadIdx.x;   // grid covers 98304
    if (id < NN) cur[id] = 0;
    unsigned short hs, ls;
    if (id < 16384){                        // We^T
        int n = id >> 7, k = id & 127;
        split1(We[(size_t)k*128 + n], hs, ls);
        wt[U_EH + id] = hs; wt[U_EL + id] = ls;
    } else if (id < 65536){                 // Wf^T (K=384)
        int local = id - 16384;
        int n = local / 384, k = local - n*384;
        split1(Wf[(size_t)k*128 + n], hs, ls);
        wt[U_FH + local] = hs; wt[U_FL + local] = ls;
    } else if (id < 98304){                 // Wa[256:512]^T (K'=256)
        int local = id - 65536;
        int n = local >> 8, kk = local & 255;
        split1(Wa[(size_t)(256+kk)*128 + n], hs, ls);
        wt[U_AH + local] = hs; wt[U_AL + local] = ls;
    }
}

// ---------------- sort pipeline ----------------
__global__ __launch_bounds__(TB) void kB_count(const int* __restrict__ dst,
                                               int* __restrict__ cur){
    int e = blockIdx.x*TB + threadIdx.x;
    atomicAdd(&cur[dst[e]], 1);
}
__global__ __launch_bounds__(TB) void kC_scan(int* __restrict__ cur,
                                              int* __restrict__ offs){
    __shared__ int part[TB];
    __shared__ int spre[TB];
    const int tid = threadIdx.x;
    const int CH = (NN + TB - 1) / TB;
    const int base = tid * CH;
    int sum = 0;
    for (int i = 0; i < CH; ++i){ int idx = base + i; if (idx < NN) sum += cur[idx]; }
    part[tid] = sum;
    __syncthreads();
    if (tid == 0){ int r = 0; for (int i = 0; i < TB; ++i){ spre[i] = r; r += part[i]; } }
    __syncthreads();
    int run = spre[tid];
    for (int i = 0; i < CH; ++i){
        int idx = base + i;
        if (idx < NN){ int c = cur[idx]; offs[idx] = run; cur[idx] = run; run += c; }
    }
}
__global__ __launch_bounds__(TB) void kD_scatter(const int* __restrict__ dst,
                                                 int* __restrict__ cur,
                                                 int* __restrict__ eidx){
    int e = blockIdx.x*TB + threadIdx.x;
    int p = atomicAdd(&cur[dst[e]], 1);
    eidx[p] = e;
}

// ---------------- k1: hn = h @ W_node (fp32 GEMM; outputs hnH/hnL split + hnP packed) ----------------
__global__ __launch_bounds__(TB) void k1_hn(const float* __restrict__ h,
                                            const float* __restrict__ Wn,
                                            unsigned short* __restrict__ hnH,
                                            unsigned short* __restrict__ hnL,
                                            unsigned* __restrict__ hnP){
    __shared__ float Ast[BK][ASTR];
    __shared__ float Bs[BK][BN];
    const int tid = threadIdx.x;
    const int rbase = blockIdx.x * BM;
    const int tc = tid & 15, tr = tid >> 4;
    const int r0 = tr*4, c0 = tc*4;
    float acc[4][8] = {};
    for (int kc = 0; kc < 128; kc += BK){
        __syncthreads();
        {
            int lr = tid >> 3, k4 = (tid & 7) << 2;
#pragma unroll
            for (int p = 0; p < 2; ++p){
                int r = p*32 + lr;
                int rr = rbase + r; if (rr >= NN) rr = NN-1;
                float4 v = *(const float4*)&h[(size_t)rr*128 + kc + k4];
                store_At(Ast, k4, r, v);
            }
        }
        load_B(Wn, kc, Bs, tid);
        __syncthreads();
        mm_chunk(Ast, Bs, r0, c0, acc);
    }
#pragma unroll
    for (int i = 0; i < 4; ++i){
        int rr = rbase + r0 + i;
        if (rr < NN){
            u16x4 h0, l0, h1, l1;
            uint4 p0, p1;
#pragma unroll
            for (int j = 0; j < 4; ++j){
                unsigned short hs, ls;
                split1(acc[i][j], hs, ls);
                h0[j] = hs; l0[j] = ls;
                ((unsigned*)&p0)[j] = ((unsigned)hs << 16) | ls;
                split1(acc[i][4+j], hs, ls);
                h1[j] = hs; l1[j] = ls;
                ((unsigned*)&p1)[j] = ((unsigned)hs << 16) | ls;
            }
            *(u16x4*)&hnH[(size_t)rr*128 + c0] = h0;
            *(u16x4*)&hnL[(size_t)rr*128 + c0] = l0;
            *(u16x4*)&hnH[(size_t)rr*128 + 64 + c0] = h1;
            *(u16x4*)&hnL[(size_t)rr*128 + 64 + c0] = l1;
            *(uint4*)&hnP[(size_t)rr*128 + c0] = p0;
            *(uint4*)&hnP[(size_t)rr*128 + 64 + c0] = p1;
        }
    }
}

// ================== k23: merged edge GEMMs, register->LDS w1 handoff ==================
// GEMM1 (4 steps): ow = ew @ We; epilogue1: p (esf-dot), global sat_w1 + ow splits.
// GEMM2 (12 steps, K-order: w1 chunks FIRST from registers, then hs, hd via gl16 gathers):
//   acc2 = w1@Wf3 + hs@Wf1 + hd@Wf2 ; epilogue2: s = attn . lrelu(acc2 + bf)
__global__ __launch_bounds__(TBM) void k23_mfma(const float* __restrict__ ew,
                                                const unsigned short* __restrict__ wtEH,
                                                const unsigned short* __restrict__ wtEL,
                                                const float* __restrict__ Wesf,
                                                const unsigned short* __restrict__ wtFH,
                                                const unsigned short* __restrict__ wtFL,
                                                const float* __restrict__ bf,
                                                const float* __restrict__ Wattn,
                                                const unsigned short* __restrict__ hnH,
                                                const unsigned short* __restrict__ hnL,
                                                const unsigned* __restrict__ hnP,
                                                const int* __restrict__ src,
                                                const int* __restrict__ dst,
                                                unsigned short* __restrict__ owH,
                                                unsigned short* __restrict__ owL,
                                                float* __restrict__ sat,
                                                float* __restrict__ s_ws){
    __shared__ __align__(16) unsigned short Ah[2][4096], Al[2][4096], Bh[2][4096], Bl[2][4096];
    __shared__ float sEsf[128], sBf[128], sAtt[128];
    __shared__ int sSrc[128], sDst[128];
    const int tid = threadIdx.x;
    const long long rbase = (long long)blockIdx.x * 128;
    const int lane = tid & 63, w = tid >> 6;
    const int ls = lane & 15, lg = lane >> 4;
    const int srow = tid >> 2, sg = tid & 3;
    const int gsw = sg ^ (srow & 3);
    const int aslot = srow*32 + (gsw << 3);
    if (tid < 128){
        sEsf[tid] = Wesf[tid]; sBf[tid] = bf[tid]; sAtt[tid] = Wattn[tid];
        sSrc[tid] = src[rbase + tid]; sDst[tid] = dst[rbase + tid];
    }
    // ---- GEMM1: ew @ We (K=128, 4 steps) ----
    f32x4 acc1[8] = {};
    auto stageA = [&](int nb, int t){
        const int kc = t*32;
        gl16(&wtEH[srow*128 + kc + gsw*8], &Bh[nb][w*512]);
        gl16(&wtEL[srow*128 + kc + gsw*8], &Bl[nb][w*512]);
        const float* p = &ew[(rbase + srow)*128 + kc + sg*8];
        float4 v0 = *(const float4*)p, v1 = *(const float4*)(p+4);
        s8v hi, lo; split8(v0, v1, hi, lo);
        *(s8v*)&Ah[nb][aslot] = hi; *(s8v*)&Al[nb][aslot] = lo;
    };
    stageA(0, 0);
    __syncthreads();
    int cur = 0;
    for (int t = 0; t < 4; ++t){
        if (t < 3) stageA(cur^1, t+1);
        s8v ah = *(const s8v*)&Ah[cur][lds_a(w*16 + ls, lg)];
        s8v al = *(const s8v*)&Al[cur][lds_a(w*16 + ls, lg)];
#pragma unroll
        for (int ct = 0; ct < 8; ++ct){
            int c = ct*16 + ls;
            s8v bh = *(const s8v*)&Bh[cur][lds_a(c,lg)];
            s8v bl = *(const s8v*)&Bl[cur][lds_a(c,lg)];
            acc1[ct] = MFMA16(ah, bh, acc1[ct]);
            acc1[ct] = MFMA16(ah, bl, acc1[ct]);
            acc1[ct] = MFMA16(al, bh, acc1[ct]);
        }
        __syncthreads();
        cur ^= 1;
    }
    // ---- epilogue1: p per row; global sat_w1 + ow splits (fire-and-forget) ----
    float pr[4];
#pragma unroll
    for (int reg = 0; reg < 4; ++reg){
        float p = 0.f;
#pragma unroll
        for (int ct = 0; ct < 8; ++ct)
            p += lrelu(acc1[ct][reg]) * sEsf[ct*16 + ls];
#pragma unroll
        for (int m = 1; m < 16; m <<= 1) p += __shfl_xor(p, m);
        pr[reg] = p;
        long long orow = rbase + w*16 + lg*4 + reg;
#pragma unroll
        for (int ct = 0; ct < 8; ++ct){
            float o = acc1[ct][reg];
            int col = ct*16 + ls;
            sat[orow*384 + 256 + col] = p * o;
            unsigned short hs_, ls_; split1(o, hs_, ls_);
            owH[orow*128 + col] = hs_;
            owL[orow*128 + col] = ls_;
        }
    }
    // ---- GEMM2: 12 steps. u<4: w1 chunk u (A from registers via ds_write, B=Wf3 k=256+32u);
    //             u>=4: hs/hd chunk (A via gl16 gathers + sat write, B=Wf k=(u-4)*32) ----
    f32x4 acc2[8] = {};
    auto stageC = [&](int nb, int t2){
        const int kb = 256 + t2*32;
        gl16(&wtFH[srow*384 + kb + gsw*8], &Bh[nb][w*512]);
        gl16(&wtFL[srow*384 + kb + gsw*8], &Bl[nb][w*512]);
#pragma unroll
        for (int q = 0; q < 2; ++q){
            int ct = 2*t2 + q;
#pragma unroll
            for (int reg = 0; reg < 4; ++reg){
                int row = w*16 + lg*4 + reg;
                int col = ct*16 + ls;
                int kl = col - t2*32;         // 0..31 within chunk
                int g = kl >> 3;
                int base = row*32 + ((g ^ (row & 3)) << 3) + (kl & 7);
                unsigned short hh, ll; split1(pr[reg] * acc1[ct][reg], hh, ll);
                Ah[nb][base] = hh;
                Al[nb][base] = ll;
            }
        }
    };
    auto stageD = [&](int nb, int t3){
        const int kc = t3*32;
        gl16(&wtFH[srow*384 + kc + gsw*8], &Bh[nb][w*512]);
        gl16(&wtFL[srow*384 + kc + gsw*8], &Bl[nb][w*512]);
        long long e = rbase + srow;
        int node = (kc < 128) ? sSrc[srow] : sDst[srow];
        int col0 = kc & 127;
        gl16(&hnH[(size_t)node*128 + col0 + gsw*8], &Ah[nb][w*512]);
        gl16(&hnL[(size_t)node*128 + col0 + gsw*8], &Al[nb][w*512]);
        const unsigned* pp = &hnP[(size_t)node*128 + col0 + sg*8];
        uint4 q0 = *(const uint4*)pp, q1 = *(const uint4*)(pp+4);
        float4 v0 = {bfp(q0.x), bfp(q0.y), bfp(q0.z), bfp(q0.w)};
        float4 v1 = {bfp(q1.x), bfp(q1.y), bfp(q1.z), bfp(q1.w)};
        *(float4*)&sat[e*384 + kc + sg*8] = v0;
        *(float4*)&sat[e*384 + kc + sg*8 + 4] = v1;
    };
    auto stage2 = [&](int nb, int u){ if (u < 4) stageC(nb, u); else stageD(nb, u - 4); };
    stage2(cur, 0);
    __syncthreads();
    for (int u = 0; u < 12; ++u){
        if (u < 11) stage2(cur^1, u+1);
        s8v ah = *(const s8v*)&Ah[cur][lds_a(w*16 + ls, lg)];
        s8v al = *(const s8v*)&Al[cur][lds_a(w*16 + ls, lg)];
#pragma unroll
        for (int ct = 0; ct < 8; ++ct){
            int c = ct*16 + ls;
            s8v bh = *(const s8v*)&Bh[cur][lds_a(c,lg)];
            s8v bl = *(const s8v*)&Bl[cur][lds_a(c,lg)];
            acc2[ct] = MFMA16(ah, bh, acc2[ct]);
            acc2[ct] = MFMA16(ah, bl, acc2[ct]);
            acc2[ct] = MFMA16(al, bh, acc2[ct]);
        }
        __syncthreads();
        cur ^= 1;
    }
    // ---- epilogue2: s = attn . lrelu(acc2 + bf) ----
#pragma unroll
    for (int reg = 0; reg < 4; ++reg){
        float p = 0.f;
#pragma unroll
        for (int ct = 0; ct < 8; ++ct){
            int col = ct*16 + ls;
            p += lrelu(acc2[ct][reg] + sBf[col]) * sAtt[col];
        }
#pragma unroll
        for (int m = 1; m < 16; m <<= 1) p += __shfl_xor(p, m);
        if (ls == 0) s_ws[rbase + w*16 + lg*4 + reg] = p;
    }
}

// ---------------- k5: wave-per-node softmax + gather-aggregate (wave-local sync) ----------------
__global__ __launch_bounds__(TB) void k5_agg(const float* __restrict__ s,
                                             const unsigned* __restrict__ hnP,
                                             const float* __restrict__ sat,
                                             const int* __restrict__ src,
                                             const int* __restrict__ eidx,
                                             const int* __restrict__ offs,
                                             const int* __restrict__ cur,
                                             float* __restrict__ hagg,
                                             float* __restrict__ den){
    __shared__ int   sEu[4][MAXD];
    __shared__ int   sEs[4][MAXD];
    __shared__ float sAl[4][MAXD];
    __shared__ float sWc[4][MAXD];
    const int wv = threadIdx.x >> 6, lane = threadIdx.x & 63;
    const int n = blockIdx.x*4 + wv;
    int* Eu = sEu[wv]; int* Es = sEs[wv];
    float* Al = sAl[wv]; float* Wc = sWc[wv];
    const int start = offs[n];
    const int deg = cur[n] - start;
    const int dc = deg < MAXD ? deg : MAXD;
    for (int i = lane; i < dc; i += 64) Eu[i] = eidx[start+i];
    wsync();                                  // all buffers are per-wave slices
    for (int i = lane; i < dc; i += 64){
        int my = Eu[i], r = 0;
        for (int j = 0; j < dc; ++j) r += (Eu[j] < my);
        Es[r] = my;
    }
    wsync();
    float lm = -3.402823466e38f;
    for (int i = lane; i < dc; i += 64){
        int e = Es[i];
        float sv = s[e];
        Wc[i] = sv;
        Eu[i] = src[e];
        lm = fmaxf(lm, sv);
    }
    for (int i = MAXD + lane; i < deg; i += 64) lm = fmaxf(lm, s[eidx[start+i]]);
#pragma unroll
    for (int m2 = 32; m2; m2 >>= 1) lm = fmaxf(lm, __shfl_xor(lm, m2));
    const float m = lm;
    wsync();
    float lsum = 0.f;
    for (int i = lane; i < dc; i += 64){
        float ev = expf(Wc[i] - m);
        Al[i] = ev;
        lsum += ev;
    }
    for (int i = MAXD + lane; i < deg; i += 64) lsum += expf(s[eidx[start+i]] - m);
#pragma unroll
    for (int m2 = 32; m2; m2 >>= 1) lsum += __shfl_xor(lsum, m2);
    const float denom = lsum;
    const float inv = (deg > 0) ? 1.f/denom : 0.f;
    for (int i = lane; i < dc; i += 64){
        float al = Al[i] * inv;
        Al[i] = al;
        Wc[i] = al * Wc[i];
    }
    wsync();
    float a0=0.f, a1=0.f, a2=0.f, a3=0.f;
    for (int i = 0; i < dc; ++i){
        int sI = Eu[i];
        size_t e = (size_t)Es[i];
        float al = Al[i], wc = Wc[i];
        unsigned p0 = hnP[(size_t)sI*128 + lane];
        unsigned p1 = hnP[(size_t)sI*128 + 64 + lane];
        float w0 = sat[e*384 + 256 + lane];
        float w1v = sat[e*384 + 256 + 64 + lane];
        a0 = fmaf(al, bfp(p0), a0);
        a1 = fmaf(al, bfp(p1), a1);
        a2 = fmaf(wc, w0, a2);
        a3 = fmaf(wc, w1v, a3);
    }
    for (int i = MAXD; i < deg; ++i){
        int e = eidx[start+i];
        float sv = s[e];
        float al = expf(sv - m) * inv;
        float wc = al * sv;
        int sI = src[e];
        a0 = fmaf(al, bfp(hnP[(size_t)sI*128 + lane]), a0);
        a1 = fmaf(al, bfp(hnP[(size_t)sI*128 + 64 + lane]), a1);
        a2 = fmaf(wc, sat[(size_t)e*384 + 256 + lane], a2);
        a3 = fmaf(wc, sat[(size_t)e*384 + 256 + 64 + lane], a3);
    }
    const size_t b = (size_t)n*256;
    hagg[b + lane] = a0;
    hagg[b + 64 + lane] = a1;
    hagg[b + 128 + lane] = a2;
    hagg[b + 192 + lane] = a3;
    if (lane == 0) den[n] = (deg > 0) ? denom : 0.f;
}

// ---------------- k6: h_new = [h_agg, hn] @ W_conc + b_conc ; indeg select ----------------
__global__ __launch_bounds__(TB) void k6_conc(const float* __restrict__ hagg,
                                              const unsigned* __restrict__ hnP,
                                              const float* __restrict__ Wc,
                                              const float* __restrict__ bc,
                                              const float* __restrict__ den,
                                              float* __restrict__ hout){
    __shared__ float Ast[BK][ASTR];
    __shared__ float Bs[BK][BN];
    __shared__ float sBc[BN];
    const int tid = threadIdx.x;
    const int rbase = blockIdx.x * BM;
    const int tc = tid & 15, tr = tid >> 4;
    const int r0 = tr*4, c0 = tc*4;
    if (tid < BN) sBc[tid] = bc[tid];
    float acc[4][8] = {};
    for (int chunk = 0; chunk < 12; ++chunk){
        int kc = chunk * BK;
        __syncthreads();
        {
            int lr = tid >> 3, k4 = (tid & 7) << 2;
#pragma unroll
            for (int p = 0; p < 2; ++p){
                int r = p*32 + lr;
                int rr = rbase + r; if (rr >= NN) rr = NN-1;
                float4 v;
                if (chunk < 8) v = *(const float4*)&hagg[(size_t)rr*256 + kc + k4];
                else {
                    int cb = (kc - 256) + k4;
                    uint4 q = *(const uint4*)&hnP[(size_t)rr*128 + cb];
                    v.x = bfp(q.x); v.y = bfp(q.y); v.z = bfp(q.z); v.w = bfp(q.w);
                }
                store_At(Ast, k4, r, v);
            }
        }
        load_B(Wc, kc, Bs, tid);
        __syncthreads();
        mm_chunk(Ast, Bs, r0, c0, acc);
    }
#pragma unroll
    for (int i = 0; i < 4; ++i){
        int rr = rbase + r0 + i;
        if (rr >= NN) continue;
        bool keep = den[rr] > 0.f;
        float o[8];
#pragma unroll
        for (int j = 0; j < 8; ++j){
            int col = (j < 4) ? (c0 + j) : (60 + c0 + j);
            float fb = bfp(hnP[(size_t)rr*128 + col]);
            o[j] = keep ? acc[i][j] + sBc[col] : fb;
        }
        float4 o0 = {o[0],o[1],o[2],o[3]}, o1 = {o[4],o[5],o[6],o[7]};
        *(float4*)&hout[(size_t)rr*128 + c0] = o0;
        *(float4*)&hout[(size_t)rr*128 + 64 + c0] = o1;
    }
}

// ---------------- kNG: Q[n][half*128..+128] = hout @ Wa_half (fp32) ----------------
__global__ __launch_bounds__(TB) void kNG(const float* __restrict__ aF,
                                          const float* __restrict__ W,   // [>=256][128] rows
                                          float* __restrict__ O){        // [N][256]
    __shared__ float Ast[BK][ASTR];
    __shared__ float Bs[BK][BN];
    const int tid = threadIdx.x;
    const int half = blockIdx.x >= NB ? 1 : 0;
    const int rbase = (blockIdx.x - half*NB) * BM;
    const float* Wp = W + (size_t)half*16384;
    const int tc = tid & 15, tr = tid >> 4;
    const int r0 = tr*4, c0 = tc*4;
    float acc[4][8] = {};
    for (int kc = 0; kc < 128; kc += BK){
        __syncthreads();
        {
            int lr = tid >> 3, k4 = (tid & 7) << 2;
#pragma unroll
            for (int p = 0; p < 2; ++p){
                int r = p*32 + lr;
                int rr = rbase + r; if (rr >= NN) rr = NN-1;
                float4 v = *(const float4*)&aF[(size_t)rr*128 + kc + k4];
                store_At(Ast, k4, r, v);
            }
        }
        load_B(Wp, kc, Bs, tid);
        __syncthreads();
        mm_chunk(Ast, Bs, r0, c0, acc);
    }
#pragma unroll
    for (int i = 0; i < 4; ++i){
        int rr = rbase + r0 + i;
        if (rr < NN){
            float4 o0 = {acc[i][0],acc[i][1],acc[i][2],acc[i][3]};
            float4 o1 = {acc[i][4],acc[i][5],acc[i][6],acc[i][7]};
            *(float4*)&O[(size_t)rr*256 + half*128 + c0] = o0;
            *(float4*)&O[(size_t)rr*256 + half*128 + 64 + c0] = o1;
        }
    }
}

// ---------------- k7p: w_out = [w_bn, ow] @ Wa[256:512] + Q1[src] + Q2[dst] ----------------
__global__ __launch_bounds__(TBM) void k7p(const unsigned short* __restrict__ owH,
                                           const unsigned short* __restrict__ owL,
                                           const float* __restrict__ sarr,
                                           const float* __restrict__ sat,
                                           const float* __restrict__ Q,
                                           const float* __restrict__ gamma,
                                           const float* __restrict__ beta,
                                           const unsigned short* __restrict__ wtH,  // [128][256]
                                           const unsigned short* __restrict__ wtL,
                                           const int* __restrict__ src,
                                           const int* __restrict__ dst,
                                           float* __restrict__ w2out){
    __shared__ __align__(16) unsigned short Ah[2][4096], Al[2][4096], Bh[2][4096], Bl[2][4096];
    __shared__ float sGam[128], sBet[128], sS[128];
    __shared__ int sSrc[128], sDst[128];
    const int tid = threadIdx.x;
    const long long rbase = (long long)blockIdx.x * 128;
    const int lane = tid & 63, w = tid >> 6;
    const int ls = lane & 15, lg = lane >> 4;
    const int srow = tid >> 2, sg = tid & 3;
    const int gsw = sg ^ (srow & 3);
    const int aslot = srow*32 + (gsw << 3);
    const float ISR = 0.9999950000374997f;  // 1/sqrt(1+1e-5)
    if (tid < 128){
        sGam[tid] = gamma[tid] * ISR; sBet[tid] = beta[tid];
        sSrc[tid] = src[rbase + tid]; sDst[tid] = dst[rbase + tid];
        sS[tid] = sarr[rbase + tid];
    }
    __syncthreads();
    f32x4 acc[8] = {};
    auto stage = [&](int nb, int t){
        const int kc = t*32;
        gl16(&wtH[srow*256 + kc + gsw*8], &Bh[nb][w*512]);
        gl16(&wtL[srow*256 + kc + gsw*8], &Bl[nb][w*512]);
        long long e = rbase + srow;
        if (kc < 128){
            int cb = kc + sg*8;
            float se = sS[srow];
            const float* p = &sat[e*384 + 256 + cb];   // w1
            float4 v0 = *(const float4*)p, v1 = *(const float4*)(p+4);
            v0.x = fmaf(v0.x*se, sGam[cb+0], sBet[cb+0]);
            v0.y = fmaf(v0.y*se, sGam[cb+1], sBet[cb+1]);
            v0.z = fmaf(v0.z*se, sGam[cb+2], sBet[cb+2]);
            v0.w = fmaf(v0.w*se, sGam[cb+3], sBet[cb+3]);
            v1.x = fmaf(v1.x*se, sGam[cb+4], sBet[cb+4]);
            v1.y = fmaf(v1.y*se, sGam[cb+5], sBet[cb+5]);
            v1.z = fmaf(v1.z*se, sGam[cb+6], sBet[cb+6]);
            v1.w = fmaf(v1.w*se, sGam[cb+7], sBet[cb+7]);
            s8v hi, lo; split8(v0, v1, hi, lo);
            *(s8v*)&Ah[nb][aslot] = hi; *(s8v*)&Al[nb][aslot] = lo;
        } else {
            int col0 = kc - 128;
            gl16(&owH[e*128 + col0 + gsw*8], &Ah[nb][w*512]);
            gl16(&owL[e*128 + col0 + gsw*8], &Al[nb][w*512]);
        }
    };
    stage(0, 0);
    __syncthreads();
    int cur = 0;
    for (int t = 0; t < 8; ++t){
        if (t+1 < 8) stage(cur^1, t+1);
        int r = w*16 + ls;
        s8v ah = *(const s8v*)&Ah[cur][r*32 + ((lg ^ (r&3)) << 3)];
        s8v al = *(const s8v*)&Al[cur][r*32 + ((lg ^ (r&3)) << 3)];
#pragma unroll
        for (int ct = 0; ct < 8; ++ct){
            int c = ct*16 + ls;
            s8v bh = *(const s8v*)&Bh[cur][c*32 + ((lg ^ (c&3)) << 3)];
            s8v bl = *(const s8v*)&Bl[cur][c*32 + ((lg ^ (c&3)) << 3)];
            acc[ct] = MFMA16(ah, bh, acc[ct]);
            acc[ct] = MFMA16(ah, bl, acc[ct]);
            acc[ct] = MFMA16(al, bh, acc[ct]);
        }
        __syncthreads();
        cur ^= 1;
    }
#pragma unroll
    for (int reg = 0; reg < 4; ++reg){
        int row = w*16 + lg*4 + reg;
        long long orow = rbase + row;
        int sI = sSrc[row], dI = sDst[row];
#pragma unroll
        for (int ct = 0; ct < 8; ++ct){
            int col = ct*16 + ls;
            w2out[orow*128 + col] = acc[ct][reg]
                                  + Q[(size_t)sI*256 + col]
                                  + Q[(size_t)dI*256 + 128 + col];
        }
    }
}

extern "C" void kernel_launch(void* const* d_in, const int* in_sizes, int n_in,
                              void* d_out, int out_size, void* d_ws, size_t ws_size,
                              hipStream_t stream){
    (void)in_sizes; (void)n_in; (void)out_size;
    const float* h       = (const float*)d_in[0];
    const float* edge_w  = (const float*)d_in[1];
    const float* W_node  = (const float*)d_in[2];
    const float* W_eedge = (const float*)d_in[3];
    const float* W_esf   = (const float*)d_in[4];
    const float* W_fuse  = (const float*)d_in[5];
    const float* b_fuse  = (const float*)d_in[6];
    const float* W_attn  = (const float*)d_in[7];
    const float* W_conc  = (const float*)d_in[8];
    const float* b_conc  = (const float*)d_in[9];
    const float* gamma   = (const float*)d_in[10];
    const float* beta    = (const float*)d_in[11];
    const float* W_aggre = (const float*)d_in[12];
    const int*   src     = (const int*)d_in[13];
    const int*   dst     = (const int*)d_in[14];

    float* out    = (float*)d_out;
    float* o_hout = out + OUT_HOUT;
    float* o_wout = out + OUT_WOUT;
    float* o_sat  = out + OUT_SAT;

    if (ws_size < (size_t)WS_FLOATS * 4) return;
    float* ws     = (float*)d_ws;
    unsigned short* w_owH = (unsigned short*)(ws + OFF_OW);
    unsigned short* w_owL = w_owH + (size_t)NE*128;     // float offset 20.48M
    unsigned short* w_hnH = (unsigned short*)(ws + OFF_HN);
    unsigned short* w_hnL = w_hnH + (size_t)NN*128;
    float* w_PQ   = ws + OFF_PQ;   // time-shared: hagg (k5->k6) then Q (kNG->k7p)
    float* w_s    = ws + OFF_S;
    float* w_den  = ws + OFF_DEN;
    int*   w_cur  = (int*)(ws + OFF_CUR);
    unsigned short* w_wt = (unsigned short*)(ws + OFF_WT);

    unsigned* w_hnP = (unsigned*)o_wout;  // packed hn (free until k7p writes w_out)
    int* w_eidx = (int*)o_hout;           // pre-k6 scratch
    int* w_offs = w_eidx + NE;

    hipLaunchKernelGGL(k_prep,    dim3(98304/TB), dim3(TB), 0, stream,
                       W_eedge, W_fuse, W_aggre, w_wt, w_cur);
    hipLaunchKernelGGL(kB_count,  dim3(NE/TB), dim3(TB), 0, stream, dst, w_cur);
    hipLaunchKernelGGL(kC_scan,   dim3(1), dim3(TB), 0, stream, w_cur, w_offs);
    hipLaunchKernelGGL(kD_scatter,dim3(NE/TB), dim3(TB), 0, stream, dst, w_cur, w_eidx);
    hipLaunchKernelGGL(k1_hn,     dim3(NB), dim3(TB), 0, stream, h, W_node,
                       w_hnH, w_hnL, w_hnP);
    hipLaunchKernelGGL(k23_mfma,  dim3(NE/128), dim3(TBM), 0, stream, edge_w,
                       w_wt + U_EH, w_wt + U_EL, W_esf,
                       w_wt + U_FH, w_wt + U_FL, b_fuse, W_attn,
                       w_hnH, w_hnL, w_hnP, src, dst,
                       w_owH, w_owL, o_sat, w_s);
    hipLaunchKernelGGL(k5_agg,    dim3(NN/4), dim3(TB), 0, stream, w_s, w_hnP, o_sat,
                       src, w_eidx, w_offs, w_cur, w_PQ, w_den);
    hipLaunchKernelGGL(k6_conc,   dim3(NB), dim3(TB), 0, stream, w_PQ,
                       w_hnP, W_conc, b_conc, w_den, o_hout);
    hipLaunchKernelGGL(kNG,       dim3(2*NB), dim3(TB), 0, stream, o_hout, W_aggre, w_PQ);
    hipLaunchKernelGGL(k7p,       dim3(NE/128), dim3(TBM), 0, stream,
                       w_owH, w_owL, w_s, o_sat, w_PQ, gamma, beta,
                       w_wt + U_AH, w_wt + U_AL, src, dst, o_wout);
}